// Round 7
// baseline (133.401 us; speedup 1.0000x reference)
//
#include <hip/hip_runtime.h>
#include <hip/hip_bf16.h>
#include <math.h>

#define S_LEN 2048
#define DMODEL 1024
#define NHEADS 16
#define DHEAD 64
#define NBATCH 2
#define MROWS (NBATCH * S_LEN)   // 4096

typedef float f32x4 __attribute__((ext_vector_type(4)));
typedef unsigned short u16x8 __attribute__((ext_vector_type(8)));
typedef __bf16 bf16x8 __attribute__((ext_vector_type(8)));

__device__ __forceinline__ f32x4 mfma16(u16x8 a, u16x8 b, f32x4 c) {
    return __builtin_amdgcn_mfma_f32_16x16x32_bf16(
        __builtin_bit_cast(bf16x8, a), __builtin_bit_cast(bf16x8, b), c, 0, 0, 0);
}

// f32 -> bf16 round-to-nearest-even
__device__ __forceinline__ unsigned short f2bf(float f) {
    unsigned int u = __builtin_bit_cast(unsigned int, f);
    u += 0x7FFFu + ((u >> 16) & 1u);
    return (unsigned short)(u >> 16);
}

// packed f32x2 -> bf16x2 (RTNE), single HW instruction
__device__ __forceinline__ unsigned int cvtpk(float lo, float hi) {
    unsigned int r;
    asm("v_cvt_pk_bf16_f32 %0, %1, %2" : "=v"(r) : "v"(lo), "v"(hi));
    return r;
}

// async global->LDS, 16B per lane; lds dest = wave-uniform base + lane*16
__device__ __forceinline__ void gl16(const void* g, void* l) {
    __builtin_amdgcn_global_load_lds(
        (const __attribute__((address_space(1))) unsigned int*)g,
        (__attribute__((address_space(3))) unsigned int*)l, 16, 0, 0);
}

// ---------------------------------------------------------------- cvt + pos
// blocks 0..2047: X. 2048..4095: Wq,Wk,Wv,Wo. 4096..4607: pos table.
__global__ __launch_bounds__(256) void cvt5(
    const float* __restrict__ X, const float* __restrict__ Wq,
    const float* __restrict__ Wk, const float* __restrict__ Wv,
    const float* __restrict__ Wo,
    unsigned short* __restrict__ Xbf, unsigned short* __restrict__ Wbf,
    float* __restrict__ pos)
{
    int b = blockIdx.x;
    if (b >= 4096) {
        int i = (b - 4096) * 256 + threadIdx.x;
        int s = i >> 6, d = i & 63;
        float theta = powf(10000.0f, (2.0f * (float)d) / 64.0f);
        float x = (float)s / theta;
        float v = (d & 1) ? cosf(x) : sinf(x);
        pos[i] = (s == 0) ? 0.0f : v;
        return;
    }
    const float* s; unsigned short* d; int t;
    if (b < 2048) { s = X; d = Xbf; t = b * 256 + threadIdx.x; }
    else {
        int z = (b - 2048) >> 9, bb = (b - 2048) & 511;
        s = (z == 0) ? Wq : (z == 1) ? Wk : (z == 2) ? Wv : Wo;
        d = Wbf + (z << 20);
        t = bb * 256 + threadIdx.x;
    }
    float4 a = *((const float4*)s + t * 2);
    float4 c = *((const float4*)s + t * 2 + 1);
    u16x8 o;
    o[0] = f2bf(a.x); o[1] = f2bf(a.y); o[2] = f2bf(a.z); o[3] = f2bf(a.w);
    o[4] = f2bf(c.x); o[5] = f2bf(c.y); o[6] = f2bf(c.z); o[7] = f2bf(c.w);
    *((u16x8*)d + t) = o;
}

// ---------------------------------------------------------------- QKV GEMM (bf16 in)
// Y = Xbf @ W^T. M=4096, N=1024, K=1024. BK=64, global_load_lds, swizzled
// source, double-buffered LDS, ONE barrier per K-step (stage overlaps MFMA).
__global__ __launch_bounds__(256) void gemm_qkv(
    const unsigned short* __restrict__ Xbf, const unsigned short* __restrict__ Wbf,
    const float* __restrict__ pos,
    unsigned short* __restrict__ qb, unsigned short* __restrict__ kb,
    unsigned short* __restrict__ vt)
{
    const int z = blockIdx.z;
    const unsigned short* __restrict__ W = Wbf + (z << 20);
    __shared__ unsigned short As[2][128 * 64];
    __shared__ unsigned short Bs[2][128 * 64];
    const int t = threadIdx.x;
    const int lane = t & 63;
    const int w = t >> 6, wr = w >> 1, wc = w & 1;
    const int m0 = blockIdx.x * 128;
    const int n0 = blockIdx.y * 128;
    const int ll = lane & 15, lg = lane >> 4;
    const int r8 = lane >> 3, ch = (lane & 7) ^ r8;

    f32x4 acc[4][4] = {};

    auto stage = [&](unsigned short* dA, unsigned short* dB, int k0) {
        #pragma unroll
        for (int c = 0; c < 4; c++) {
            const int row = c * 32 + w * 8 + r8;
            gl16(Xbf + (m0 + row) * 1024 + k0 + ch * 8, dA + (c * 32 + w * 8) * 64);
            gl16(W   + (n0 + row) * 1024 + k0 + ch * 8, dB + (c * 32 + w * 8) * 64);
        }
    };
    auto compute = [&](const unsigned short* SA, const unsigned short* SB) {
        #pragma unroll
        for (int kk = 0; kk < 2; kk++) {
            u16x8 af[4], bfv[4];
            #pragma unroll
            for (int m = 0; m < 4; m++) {
                const int row = wr * 64 + m * 16 + ll;
                af[m] = *(const u16x8*)&SA[row * 64 + (((kk * 4 + lg) ^ (row & 7)) * 8)];
            }
            #pragma unroll
            for (int n = 0; n < 4; n++) {
                const int row = wc * 64 + n * 16 + ll;
                bfv[n] = *(const u16x8*)&SB[row * 64 + (((kk * 4 + lg) ^ (row & 7)) * 8)];
            }
            __builtin_amdgcn_s_setprio(1);
            #pragma unroll
            for (int m = 0; m < 4; m++)
                #pragma unroll
                for (int n = 0; n < 4; n++)
                    acc[m][n] = mfma16(af[m], bfv[n], acc[m][n]);
            __builtin_amdgcn_s_setprio(0);
        }
    };

    stage(As[0], Bs[0], 0);
    __syncthreads();
    for (int p = 0; p < 8; p++) {
        stage(As[1], Bs[1], p * 128 + 64);
        compute(As[0], Bs[0]);
        __syncthreads();
        if (p < 7) stage(As[0], Bs[0], p * 128 + 128);
        compute(As[1], Bs[1]);
        __syncthreads();
    }

    #pragma unroll
    for (int m = 0; m < 4; m++) {
        #pragma unroll
        for (int n = 0; n < 4; n++) {
            #pragma unroll
            for (int r = 0; r < 4; r++) {
                int row = m0 + wr * 64 + m * 16 + lg * 4 + r;   // b*2048 + s
                int col = n0 + wc * 64 + n * 16 + ll;           // h*64 + d
                float v = acc[m][n][r];
                int b = row >> 11, s = row & 2047;
                int h = col >> 6, d = col & 63;
                if (z == 2) {
                    vt[(((b * NHEADS + h) * 64) + d) * S_LEN + s] = f2bf(v);   // V^T
                } else {
                    v += pos[s * 64 + d];
                    // Q: fold 1/sqrt(d_k) * log2(e) so softmax can use exp2
                    if (z == 0) v *= 0.1803368801111244f;
                    unsigned short* dst = (z == 0) ? qb : kb;
                    dst[(((b * NHEADS + h) * S_LEN) + s) * 64 + d] = f2bf(v);
                }
            }
        }
    }
}

// ---------------------------------------------------------------- attention
// grid (16 qt, 32 bh), 8 waves x 512 thr, QBLK=128 (wave owns 16 q-rows).
// K/V staged once per 128 q-rows (1 gl16 K + 1 gl16 V per wave per tile),
// statically double-buffered. nkv = 2qt+2 always even; diagonal pair peeled.
// Fixed-shift softmax exp2(sc) (C=0 exact by shift invariance; |sc| <~ 7).
__global__ __launch_bounds__(512, 4) void attn_kernel(
    const unsigned short* __restrict__ qb,
    const unsigned short* __restrict__ kb,
    const unsigned short* __restrict__ vt,
    unsigned short* __restrict__ attnb)
{
    __shared__ unsigned short Klds[2][64 * 64];   // 8KB each
    __shared__ unsigned short Vlds[2][64 * 64];
    __shared__ unsigned short Plds[8][16 * 64];   // per-wave 2KB; total LDS = 49152

    const int bh = blockIdx.y;
    const int x = blockIdx.x;
    const int qt = (bh < 16) ? (15 - x) : x;      // pair long+short across co-resident halves

    const int lane = threadIdx.x & 63;
    const int w = threadIdx.x >> 6;               // 0..7
    const int lg = lane >> 4, ll = lane & 15;
    const int r8 = lane >> 3, ch = (lane & 7) ^ r8;

    const unsigned short* Q = qb + bh * (S_LEN * 64);
    const unsigned short* K = kb + bh * (S_LEN * 64);
    const unsigned short* V = vt + bh * (64 * S_LEN);
    const int q0 = qt * 128 + w * 16;             // wave q-base

    u16x8 qf0 = *(const u16x8*)(Q + (q0 + ll) * 64 + lg * 8);
    u16x8 qf1 = *(const u16x8*)(Q + (q0 + ll) * 64 + 32 + lg * 8);

    f32x4 o_acc[4] = {};
    float l_part = 0.0f;

    // ---- precomputed LDS byte addresses ----
    const int sw0 = ((0 * 4 + lg) ^ (ll & 7)) * 16;
    const int sw1 = ((1 * 4 + lg) ^ (ll & 7)) * 16;
    const int llb = ll * 128;
    const char* k0p0 = (const char*)&Klds[0][0] + llb + sw0;
    const char* k0p1 = (const char*)&Klds[0][0] + llb + sw1;
    const char* k1p0 = (const char*)&Klds[1][0] + llb + sw0;
    const char* k1p1 = (const char*)&Klds[1][0] + llb + sw1;
    const char* v0p0 = (const char*)&Vlds[0][0] + llb + sw0;
    const char* v0p1 = (const char*)&Vlds[0][0] + llb + sw1;
    const char* v1p0 = (const char*)&Vlds[1][0] + llb + sw0;
    const char* v1p1 = (const char*)&Vlds[1][0] + llb + sw1;
    // P write: addr = ((ll*128+lg*8) ^ (E&16)) + ((f*32) ^ (E&96)),  E=(ll&7)<<4
    const int E = (ll & 7) << 4;
    char* pwb = (char*)&Plds[w][0] + ((llb + lg * 8) ^ (E & 16));
    const int pw_o0 = 0 ^ (E & 96), pw_o1 = 32 ^ (E & 96);
    const int pw_o2 = 64 ^ (E & 96), pw_o3 = 96 ^ (E & 96);
    const char* pr0 = (const char*)&Plds[w][0] + llb + sw0;
    const char* pr1 = (const char*)&Plds[w][0] + llb + sw1;
    // staging dests (wave-uniform, 8 rows per wave) and running global srcs
    unsigned short* kd0 = &Klds[0][(w * 8) * 64];
    unsigned short* kd1 = &Klds[1][(w * 8) * 64];
    unsigned short* vd0 = &Vlds[0][(w * 8) * 64];
    unsigned short* vd1 = &Vlds[1][(w * 8) * 64];
    const unsigned short* gk = K + (w * 8 + r8) * 64 + ch * 8;
    const unsigned short* gv = V + (w * 8 + r8) * S_LEN + ch * 8;
    // diagonal thresholds: mask sc[f][r] iff f*16+r > thr (tile 2qt: thr; 2qt+1: thr-64)
    const int dthr = w * 16 + ll - lg * 4;

    auto stage2 = [&](unsigned short* kd, unsigned short* vd) {
        gl16(gk, kd);
        gl16(gv, vd);
        gk += 64 * 64;   // next KV tile: +64 K-rows
        gv += 64;        // next KV tile: +64 cols of V^T
    };

    auto tile_body = [&](const char* kp0, const char* kp1,
                         const char* vp0, const char* vp1, bool masked, int thr) {
        f32x4 sc[4] = {};
        __builtin_amdgcn_s_setprio(1);
        #pragma unroll
        for (int f = 0; f < 4; f++) {
            const u16x8 kfa = *(const u16x8*)(kp0 + f * 2048);
            sc[f] = mfma16(kfa, qf0, sc[f]);
            const u16x8 kfb = *(const u16x8*)(kp1 + f * 2048);
            sc[f] = mfma16(kfb, qf1, sc[f]);
        }
        __builtin_amdgcn_s_setprio(0);
        if (masked) {
            #pragma unroll
            for (int f = 0; f < 4; f++)
                #pragma unroll
                for (int r = 0; r < 4; r++)
                    if (f * 16 + r > thr) sc[f][r] = -1.0e9f;
        }
        float ts = 0.0f;
        #pragma unroll
        for (int f = 0; f < 4; f++)
            #pragma unroll
            for (int r = 0; r < 4; r++) {
                const float p = __builtin_amdgcn_exp2f(sc[f][r]);
                sc[f][r] = p;
                ts += p;
            }
        l_part += ts;
        *(unsigned long long*)(pwb + pw_o0) =
            (unsigned long long)cvtpk(sc[0][0], sc[0][1]) | ((unsigned long long)cvtpk(sc[0][2], sc[0][3]) << 32);
        *(unsigned long long*)(pwb + pw_o1) =
            (unsigned long long)cvtpk(sc[1][0], sc[1][1]) | ((unsigned long long)cvtpk(sc[1][2], sc[1][3]) << 32);
        *(unsigned long long*)(pwb + pw_o2) =
            (unsigned long long)cvtpk(sc[2][0], sc[2][1]) | ((unsigned long long)cvtpk(sc[2][2], sc[2][3]) << 32);
        *(unsigned long long*)(pwb + pw_o3) =
            (unsigned long long)cvtpk(sc[3][0], sc[3][1]) | ((unsigned long long)cvtpk(sc[3][2], sc[3][3]) << 32);
        const u16x8 pf0 = *(const u16x8*)pr0;
        const u16x8 pf1 = *(const u16x8*)pr1;
        __builtin_amdgcn_s_setprio(1);
        #pragma unroll
        for (int f = 0; f < 4; f++) {
            o_acc[f] = mfma16(pf0, *(const u16x8*)(vp0 + f * 2048), o_acc[f]);
            o_acc[f] = mfma16(pf1, *(const u16x8*)(vp1 + f * 2048), o_acc[f]);
        }
        __builtin_amdgcn_s_setprio(0);
    };

    stage2(kd0, vd0);   // tile 0 -> buf0

    for (int p = 0; p < qt; p++) {         // qt pairs of full (unmasked) tiles
        __syncthreads();
        stage2(kd1, vd1);                  // tile 2p+1 -> buf1
        tile_body(k0p0, k0p1, v0p0, v0p1, false, 0);
        __syncthreads();
        stage2(kd0, vd0);                  // tile 2p+2 -> buf0
        tile_body(k1p0, k1p1, v1p0, v1p1, false, 0);
    }
    // diagonal pair (tiles 2qt in buf0, 2qt+1 in buf1)
    __syncthreads();
    stage2(kd1, vd1);                      // tile 2qt+1 -> buf1
    tile_body(k0p0, k0p1, v0p0, v0p1, true, dthr);
    __syncthreads();
    tile_body(k1p0, k1p1, v1p0, v1p1, true, dthr - 64);

    // one-time l reduction: lane (lg,ll) holds partial over its kv-subset of q=ll
    l_part += __shfl_xor(l_part, 16);
    l_part += __shfl_xor(l_part, 32);

    const int bb = bh >> 4, h = bh & 15;
    float lr0 = 1.0f / __shfl(l_part, lg * 4 + 0);
    float lr1 = 1.0f / __shfl(l_part, lg * 4 + 1);
    float lr2 = 1.0f / __shfl(l_part, lg * 4 + 2);
    float lr3 = 1.0f / __shfl(l_part, lg * 4 + 3);
    #pragma unroll
    for (int f = 0; f < 4; f++) {
        const int colbase = h * 64 + f * 16 + ll;
        attnb[(bb * S_LEN + q0 + lg * 4 + 0) * DMODEL + colbase] = f2bf(o_acc[f][0] * lr0);
        attnb[(bb * S_LEN + q0 + lg * 4 + 1) * DMODEL + colbase] = f2bf(o_acc[f][1] * lr1);
        attnb[(bb * S_LEN + q0 + lg * 4 + 2) * DMODEL + colbase] = f2bf(o_acc[f][2] * lr2);
        attnb[(bb * S_LEN + q0 + lg * 4 + 3) * DMODEL + colbase] = f2bf(o_acc[f][3] * lr3);
    }
}

// ---------------------------------------------------------------- out GEMM
// out = attn @ Wo^T + X. A bf16, B = Wbf+3M, out f32. Same dbuf structure.
__global__ __launch_bounds__(256) void gemm_out(
    const unsigned short* __restrict__ Abf,
    const unsigned short* __restrict__ Wbf,
    const float* __restrict__ X,
    float* __restrict__ out)
{
    const unsigned short* __restrict__ W = Wbf + (3u << 20);
    __shared__ unsigned short As[2][128 * 64];
    __shared__ unsigned short Bs[2][128 * 64];
    const int t = threadIdx.x;
    const int lane = t & 63;
    const int w = t >> 6, wr = w >> 1, wc = w & 1;
    const int m0 = blockIdx.x * 128;
    const int n0 = blockIdx.y * 128;
    const int ll = lane & 15, lg = lane >> 4;
    const int r8 = lane >> 3, ch = (lane & 7) ^ r8;

    f32x4 acc[4][4] = {};

    auto stage = [&](unsigned short* dA, unsigned short* dB, int k0) {
        #pragma unroll
        for (int c = 0; c < 4; c++) {
            const int row = c * 32 + w * 8 + r8;
            gl16(Abf + (m0 + row) * 1024 + k0 + ch * 8, dA + (c * 32 + w * 8) * 64);
            gl16(W   + (n0 + row) * 1024 + k0 + ch * 8, dB + (c * 32 + w * 8) * 64);
        }
    };
    auto compute = [&](const unsigned short* SA, const unsigned short* SB) {
        #pragma unroll
        for (int kk = 0; kk < 2; kk++) {
            u16x8 af[4], bfv[4];
            #pragma unroll
            for (int m = 0; m < 4; m++) {
                const int row = wr * 64 + m * 16 + ll;
                af[m] = *(const u16x8*)&SA[row * 64 + (((kk * 4 + lg) ^ (row & 7)) * 8)];
            }
            #pragma unroll
            for (int n = 0; n < 4; n++) {
                const int row = wc * 64 + n * 16 + ll;
                bfv[n] = *(const u16x8*)&SB[row * 64 + (((kk * 4 + lg) ^ (row & 7)) * 8)];
            }
            __builtin_amdgcn_s_setprio(1);
            #pragma unroll
            for (int m = 0; m < 4; m++)
                #pragma unroll
                for (int n = 0; n < 4; n++)
                    acc[m][n] = mfma16(af[m], bfv[n], acc[m][n]);
            __builtin_amdgcn_s_setprio(0);
        }
    };

    stage(As[0], Bs[0], 0);
    __syncthreads();
    for (int p = 0; p < 8; p++) {
        stage(As[1], Bs[1], p * 128 + 64);
        compute(As[0], Bs[0]);
        __syncthreads();
        if (p < 7) stage(As[0], Bs[0], p * 128 + 128);
        compute(As[1], Bs[1]);
        __syncthreads();
    }

    #pragma unroll
    for (int m = 0; m < 4; m++)
        #pragma unroll
        for (int n = 0; n < 4; n++)
            #pragma unroll
            for (int r = 0; r < 4; r++) {
                int row = m0 + wr * 64 + m * 16 + lg * 4 + r;
                int col = n0 + wc * 64 + n * 16 + ll;
                out[row * 1024 + col] = acc[m][n][r] + X[row * 1024 + col];
            }
}

// ---------------------------------------------------------------- launch
extern "C" void kernel_launch(void* const* d_in, const int* in_sizes, int n_in,
                              void* d_out, int out_size, void* d_ws, size_t ws_size,
                              hipStream_t stream) {
    const float* X  = (const float*)d_in[0];
    const float* Wq = (const float*)d_in[1];
    const float* Wk = (const float*)d_in[2];
    const float* Wv = (const float*)d_in[3];
    const float* Wo = (const float*)d_in[4];
    float* out = (float*)d_out;

    char* ws = (char*)d_ws;
    float*          pos  = (float*)(ws);                                   // 512 KB
    unsigned short* Xbf  = (unsigned short*)(ws + (512u << 10));           // 8 MB (reused as attb)
    unsigned short* Wbf  = (unsigned short*)(ws + (512u << 10) + (8u  << 20));  // 8 MB (4 stacked)
    unsigned short* qb   = (unsigned short*)(ws + (512u << 10) + (16u << 20));
    unsigned short* kb   = (unsigned short*)(ws + (512u << 10) + (24u << 20));
    unsigned short* vt   = (unsigned short*)(ws + (512u << 10) + (32u << 20));
    unsigned short* attb = Xbf;   // Xbf dead after gemm_qkv; reuse for attn output

    cvt5<<<dim3(4608), dim3(256), 0, stream>>>(X, Wq, Wk, Wv, Wo, Xbf, Wbf, pos);
    gemm_qkv<<<dim3(32, 8, 3), dim3(256), 0, stream>>>(Xbf, Wbf, pos, qb, kb, vt);
    attn_kernel<<<dim3(16, 32), dim3(512), 0, stream>>>(qb, kb, vt, attb);
    gemm_out<<<dim3(32, 8), dim3(256), 0, stream>>>(attb, Wbf, X, out);
}

// Round 8
// 113.799 us; speedup vs baseline: 1.1723x; 1.1723x over previous
//
#include <hip/hip_runtime.h>
#include <hip/hip_bf16.h>
#include <math.h>

#define S_LEN 2048
#define DMODEL 1024
#define NHEADS 16
#define DHEAD 64
#define NBATCH 2
#define MROWS (NBATCH * S_LEN)   // 4096

typedef float f32x4 __attribute__((ext_vector_type(4)));
typedef unsigned short u16x8 __attribute__((ext_vector_type(8)));
typedef __bf16 bf16x8 __attribute__((ext_vector_type(8)));

__device__ __forceinline__ f32x4 mfma16(u16x8 a, u16x8 b, f32x4 c) {
    return __builtin_amdgcn_mfma_f32_16x16x32_bf16(
        __builtin_bit_cast(bf16x8, a), __builtin_bit_cast(bf16x8, b), c, 0, 0, 0);
}

// f32 -> bf16 round-to-nearest-even
__device__ __forceinline__ unsigned short f2bf(float f) {
    unsigned int u = __builtin_bit_cast(unsigned int, f);
    u += 0x7FFFu + ((u >> 16) & 1u);
    return (unsigned short)(u >> 16);
}

// packed f32x2 -> bf16x2 (RTNE), single HW instruction
__device__ __forceinline__ unsigned int cvtpk(float lo, float hi) {
    unsigned int r;
    asm("v_cvt_pk_bf16_f32 %0, %1, %2" : "=v"(r) : "v"(lo), "v"(hi));
    return r;
}

// async global->LDS, 16B per lane; lds dest = wave-uniform base + lane*16
__device__ __forceinline__ void gl16(const void* g, void* l) {
    __builtin_amdgcn_global_load_lds(
        (const __attribute__((address_space(1))) unsigned int*)g,
        (__attribute__((address_space(3))) unsigned int*)l, 16, 0, 0);
}

// ---------------------------------------------------------------- cvt + pos
// blocks 0..2047: X. 2048..4095: Wq,Wk,Wv,Wo. 4096..4607: pos table.
__global__ __launch_bounds__(256) void cvt5(
    const float* __restrict__ X, const float* __restrict__ Wq,
    const float* __restrict__ Wk, const float* __restrict__ Wv,
    const float* __restrict__ Wo,
    unsigned short* __restrict__ Xbf, unsigned short* __restrict__ Wbf,
    float* __restrict__ pos)
{
    int b = blockIdx.x;
    if (b >= 4096) {
        int i = (b - 4096) * 256 + threadIdx.x;
        int s = i >> 6, d = i & 63;
        float theta = powf(10000.0f, (2.0f * (float)d) / 64.0f);
        float x = (float)s / theta;
        float v = (d & 1) ? cosf(x) : sinf(x);
        pos[i] = (s == 0) ? 0.0f : v;
        return;
    }
    const float* s; unsigned short* d; int t;
    if (b < 2048) { s = X; d = Xbf; t = b * 256 + threadIdx.x; }
    else {
        int z = (b - 2048) >> 9, bb = (b - 2048) & 511;
        s = (z == 0) ? Wq : (z == 1) ? Wk : (z == 2) ? Wv : Wo;
        d = Wbf + (z << 20);
        t = bb * 256 + threadIdx.x;
    }
    float4 a = *((const float4*)s + t * 2);
    float4 c = *((const float4*)s + t * 2 + 1);
    u16x8 o;
    o[0] = f2bf(a.x); o[1] = f2bf(a.y); o[2] = f2bf(a.z); o[3] = f2bf(a.w);
    o[4] = f2bf(c.x); o[5] = f2bf(c.y); o[6] = f2bf(c.z); o[7] = f2bf(c.w);
    *((u16x8*)d + t) = o;
}

// ---------------------------------------------------------------- QKV GEMM (bf16 in)
// Single fused dispatch: grid (32, 24); by>>3 selects Q/K/V, (by&7) the N panel.
// Y = Xbf @ W^T. BK=64, global_load_lds, pre-swizzled source, 2-barrier K-loop
// (r5 proven structure: overlap via 3 co-resident blocks/CU).
__global__ __launch_bounds__(256) void gemm_qkv(
    const unsigned short* __restrict__ Xbf, const unsigned short* __restrict__ Wbf,
    const float* __restrict__ pos,
    unsigned short* __restrict__ qb, unsigned short* __restrict__ kb,
    unsigned short* __restrict__ vt)
{
    const int z = blockIdx.y >> 3;
    const unsigned short* __restrict__ W = Wbf + (z << 20);
    __shared__ unsigned short As[128 * 64];
    __shared__ unsigned short Bs[128 * 64];
    const int t = threadIdx.x;
    const int lane = t & 63;
    const int w = t >> 6, wr = w >> 1, wc = w & 1;
    const int m0 = blockIdx.x * 128;
    const int n0 = (blockIdx.y & 7) * 128;
    const int ll = lane & 15, lg = lane >> 4;
    const int r8 = lane >> 3, ch = (lane & 7) ^ r8;   // pre-swizzled source chunk

    f32x4 acc[4][4] = {};

    for (int k0 = 0; k0 < 1024; k0 += 64) {
        __syncthreads();
        #pragma unroll
        for (int c = 0; c < 4; c++) {
            const int row = c * 32 + w * 8 + r8;
            gl16(Xbf + (m0 + row) * 1024 + k0 + ch * 8, &As[(c * 32 + w * 8) * 64]);
            gl16(W   + (n0 + row) * 1024 + k0 + ch * 8, &Bs[(c * 32 + w * 8) * 64]);
        }
        __syncthreads();
        #pragma unroll
        for (int kk = 0; kk < 2; kk++) {
            u16x8 af[4], bfv[4];
            #pragma unroll
            for (int m = 0; m < 4; m++) {
                const int row = wr * 64 + m * 16 + ll;
                af[m] = *(const u16x8*)&As[row * 64 + (((kk * 4 + lg) ^ (row & 7)) * 8)];
            }
            #pragma unroll
            for (int n = 0; n < 4; n++) {
                const int row = wc * 64 + n * 16 + ll;
                bfv[n] = *(const u16x8*)&Bs[row * 64 + (((kk * 4 + lg) ^ (row & 7)) * 8)];
            }
            __builtin_amdgcn_s_setprio(1);
            #pragma unroll
            for (int m = 0; m < 4; m++)
                #pragma unroll
                for (int n = 0; n < 4; n++)
                    acc[m][n] = mfma16(af[m], bfv[n], acc[m][n]);
            __builtin_amdgcn_s_setprio(0);
        }
    }

    #pragma unroll
    for (int m = 0; m < 4; m++) {
        #pragma unroll
        for (int n = 0; n < 4; n++) {
            #pragma unroll
            for (int r = 0; r < 4; r++) {
                int row = m0 + wr * 64 + m * 16 + lg * 4 + r;   // b*2048 + s
                int col = n0 + wc * 64 + n * 16 + ll;           // h*64 + d
                float v = acc[m][n][r];
                int b = row >> 11, s = row & 2047;
                int h = col >> 6, d = col & 63;
                if (z == 2) {
                    vt[(((b * NHEADS + h) * 64) + d) * S_LEN + s] = f2bf(v);   // V^T
                } else {
                    v += pos[s * 64 + d];
                    // Q: fold 1/sqrt(d_k) * log2(e) so softmax can use exp2
                    if (z == 0) v *= 0.1803368801111244f;
                    unsigned short* dst = (z == 0) ? qb : kb;
                    dst[(((b * NHEADS + h) * S_LEN) + s) * 64 + d] = f2bf(v);
                }
            }
        }
    }
}

// ---------------------------------------------------------------- attention
// grid (16 qt, 32 bh), 8 waves x 512 thr, QBLK=128 (wave owns 16 q-rows).
// K/V staged once per 128 q-rows, statically double-buffered (16KB KV LDS).
// nkv = 2qt+2 always even; diagonal pair peeled; waves 0-3 skip the second
// diagonal tile (fully masked for them). Fixed-shift softmax exp2(sc).
__global__ __launch_bounds__(512, 4) void attn_kernel(
    const unsigned short* __restrict__ qb,
    const unsigned short* __restrict__ kb,
    const unsigned short* __restrict__ vt,
    unsigned short* __restrict__ attnb)
{
    __shared__ unsigned short Klds[2][64 * 64];   // 8KB each
    __shared__ unsigned short Vlds[2][64 * 64];
    __shared__ unsigned short Plds[8][16 * 64];   // per-wave 2KB; total LDS = 49152

    const int bh = blockIdx.y;
    const int x = blockIdx.x;
    const int qt = (bh < 16) ? (15 - x) : x;      // pair long+short across halves

    const int lane = threadIdx.x & 63;
    const int w = threadIdx.x >> 6;               // 0..7
    const int lg = lane >> 4, ll = lane & 15;
    const int r8 = lane >> 3, ch = (lane & 7) ^ r8;

    const unsigned short* Q = qb + bh * (S_LEN * 64);
    const unsigned short* K = kb + bh * (S_LEN * 64);
    const unsigned short* V = vt + bh * (64 * S_LEN);
    const int q0 = qt * 128 + w * 16;             // wave q-base

    u16x8 qf0 = *(const u16x8*)(Q + (q0 + ll) * 64 + lg * 8);
    u16x8 qf1 = *(const u16x8*)(Q + (q0 + ll) * 64 + 32 + lg * 8);

    f32x4 o_acc[4] = {};
    float l_part = 0.0f;

    // ---- precomputed LDS byte addresses ----
    const int sw0 = ((0 * 4 + lg) ^ (ll & 7)) * 16;
    const int sw1 = ((1 * 4 + lg) ^ (ll & 7)) * 16;
    const int llb = ll * 128;
    const char* k0p0 = (const char*)&Klds[0][0] + llb + sw0;
    const char* k0p1 = (const char*)&Klds[0][0] + llb + sw1;
    const char* k1p0 = (const char*)&Klds[1][0] + llb + sw0;
    const char* k1p1 = (const char*)&Klds[1][0] + llb + sw1;
    const char* v0p0 = (const char*)&Vlds[0][0] + llb + sw0;
    const char* v0p1 = (const char*)&Vlds[0][0] + llb + sw1;
    const char* v1p0 = (const char*)&Vlds[1][0] + llb + sw0;
    const char* v1p1 = (const char*)&Vlds[1][0] + llb + sw1;
    // P write: addr = ((ll*128+lg*8) ^ (E&16)) + ((f*32) ^ (E&96)),  E=(ll&7)<<4
    const int E = (ll & 7) << 4;
    char* pwb = (char*)&Plds[w][0] + ((llb + lg * 8) ^ (E & 16));
    const int pw_o0 = 0 ^ (E & 96), pw_o1 = 32 ^ (E & 96);
    const int pw_o2 = 64 ^ (E & 96), pw_o3 = 96 ^ (E & 96);
    const char* pr0 = (const char*)&Plds[w][0] + llb + sw0;
    const char* pr1 = (const char*)&Plds[w][0] + llb + sw1;
    // staging dests (wave-uniform, 8 rows per wave) and running global srcs
    unsigned short* kd0 = &Klds[0][(w * 8) * 64];
    unsigned short* kd1 = &Klds[1][(w * 8) * 64];
    unsigned short* vd0 = &Vlds[0][(w * 8) * 64];
    unsigned short* vd1 = &Vlds[1][(w * 8) * 64];
    const unsigned short* gk = K + (w * 8 + r8) * 64 + ch * 8;
    const unsigned short* gv = V + (w * 8 + r8) * S_LEN + ch * 8;
    // diagonal thresholds: mask sc[f][r] iff f*16+r > thr (tile 2qt: thr; 2qt+1: thr-64)
    const int dthr = w * 16 + ll - lg * 4;

    auto stage2 = [&](unsigned short* kd, unsigned short* vd) {
        gl16(gk, kd);
        gl16(gv, vd);
        gk += 64 * 64;   // next KV tile: +64 K-rows
        gv += 64;        // next KV tile: +64 cols of V^T
    };

    auto tile_body = [&](const char* kp0, const char* kp1,
                         const char* vp0, const char* vp1, bool masked, int thr) {
        f32x4 sc[4] = {};
        __builtin_amdgcn_s_setprio(1);
        #pragma unroll
        for (int f = 0; f < 4; f++) {
            const u16x8 kfa = *(const u16x8*)(kp0 + f * 2048);
            sc[f] = mfma16(kfa, qf0, sc[f]);
            const u16x8 kfb = *(const u16x8*)(kp1 + f * 2048);
            sc[f] = mfma16(kfb, qf1, sc[f]);
        }
        __builtin_amdgcn_s_setprio(0);
        if (masked) {
            #pragma unroll
            for (int f = 0; f < 4; f++)
                #pragma unroll
                for (int r = 0; r < 4; r++)
                    if (f * 16 + r > thr) sc[f][r] = -1.0e9f;
        }
        float ts = 0.0f;
        #pragma unroll
        for (int f = 0; f < 4; f++)
            #pragma unroll
            for (int r = 0; r < 4; r++) {
                const float p = __builtin_amdgcn_exp2f(sc[f][r]);
                sc[f][r] = p;
                ts += p;
            }
        l_part += ts;
        *(unsigned long long*)(pwb + pw_o0) =
            (unsigned long long)cvtpk(sc[0][0], sc[0][1]) | ((unsigned long long)cvtpk(sc[0][2], sc[0][3]) << 32);
        *(unsigned long long*)(pwb + pw_o1) =
            (unsigned long long)cvtpk(sc[1][0], sc[1][1]) | ((unsigned long long)cvtpk(sc[1][2], sc[1][3]) << 32);
        *(unsigned long long*)(pwb + pw_o2) =
            (unsigned long long)cvtpk(sc[2][0], sc[2][1]) | ((unsigned long long)cvtpk(sc[2][2], sc[2][3]) << 32);
        *(unsigned long long*)(pwb + pw_o3) =
            (unsigned long long)cvtpk(sc[3][0], sc[3][1]) | ((unsigned long long)cvtpk(sc[3][2], sc[3][3]) << 32);
        const u16x8 pf0 = *(const u16x8*)pr0;
        const u16x8 pf1 = *(const u16x8*)pr1;
        __builtin_amdgcn_s_setprio(1);
        #pragma unroll
        for (int f = 0; f < 4; f++) {
            o_acc[f] = mfma16(pf0, *(const u16x8*)(vp0 + f * 2048), o_acc[f]);
            o_acc[f] = mfma16(pf1, *(const u16x8*)(vp1 + f * 2048), o_acc[f]);
        }
        __builtin_amdgcn_s_setprio(0);
    };

    stage2(kd0, vd0);   // tile 0 -> buf0

    for (int p = 0; p < qt; p++) {         // qt pairs of full (unmasked) tiles
        __syncthreads();
        stage2(kd1, vd1);                  // tile 2p+1 -> buf1
        tile_body(k0p0, k0p1, v0p0, v0p1, false, 0);
        __syncthreads();
        stage2(kd0, vd0);                  // tile 2p+2 -> buf0
        tile_body(k1p0, k1p1, v1p0, v1p1, false, 0);
    }
    // diagonal pair (tiles 2qt in buf0, 2qt+1 in buf1)
    __syncthreads();
    stage2(kd1, vd1);                      // tile 2qt+1 -> buf1
    tile_body(k0p0, k0p1, v0p0, v0p1, true, dthr);
    __syncthreads();
    if (w >= 4)                            // waves 0-3: tile 2qt+1 fully masked
        tile_body(k1p0, k1p1, v1p0, v1p1, true, dthr - 64);

    // one-time l reduction: lane (lg,ll) holds partial over its kv-subset of q=ll
    l_part += __shfl_xor(l_part, 16);
    l_part += __shfl_xor(l_part, 32);

    const int bb = bh >> 4, h = bh & 15;
    float lr0 = 1.0f / __shfl(l_part, lg * 4 + 0);
    float lr1 = 1.0f / __shfl(l_part, lg * 4 + 1);
    float lr2 = 1.0f / __shfl(l_part, lg * 4 + 2);
    float lr3 = 1.0f / __shfl(l_part, lg * 4 + 3);
    #pragma unroll
    for (int f = 0; f < 4; f++) {
        const int colbase = h * 64 + f * 16 + ll;
        attnb[(bb * S_LEN + q0 + lg * 4 + 0) * DMODEL + colbase] = f2bf(o_acc[f][0] * lr0);
        attnb[(bb * S_LEN + q0 + lg * 4 + 1) * DMODEL + colbase] = f2bf(o_acc[f][1] * lr1);
        attnb[(bb * S_LEN + q0 + lg * 4 + 2) * DMODEL + colbase] = f2bf(o_acc[f][2] * lr2);
        attnb[(bb * S_LEN + q0 + lg * 4 + 3) * DMODEL + colbase] = f2bf(o_acc[f][3] * lr3);
    }
}

// ---------------------------------------------------------------- out GEMM
// out = attn @ Wo^T + X. A bf16, B = Wbf+3M, out f32. r5 proven structure.
__global__ __launch_bounds__(256) void gemm_out(
    const unsigned short* __restrict__ Abf,
    const unsigned short* __restrict__ Wbf,
    const float* __restrict__ X,
    float* __restrict__ out)
{
    const unsigned short* __restrict__ W = Wbf + (3u << 20);
    __shared__ unsigned short As[128 * 64];
    __shared__ unsigned short Bs[128 * 64];
    const int t = threadIdx.x;
    const int lane = t & 63;
    const int w = t >> 6, wr = w >> 1, wc = w & 1;
    const int m0 = blockIdx.x * 128;
    const int n0 = blockIdx.y * 128;
    const int ll = lane & 15, lg = lane >> 4;
    const int r8 = lane >> 3, ch = (lane & 7) ^ r8;

    f32x4 acc[4][4] = {};

    for (int k0 = 0; k0 < 1024; k0 += 64) {
        __syncthreads();
        #pragma unroll
        for (int c = 0; c < 4; c++) {
            const int row = c * 32 + w * 8 + r8;
            gl16(Abf + (m0 + row) * 1024 + k0 + ch * 8, &As[(c * 32 + w * 8) * 64]);
            gl16(W   + (n0 + row) * 1024 + k0 + ch * 8, &Bs[(c * 32 + w * 8) * 64]);
        }
        __syncthreads();
        #pragma unroll
        for (int kk = 0; kk < 2; kk++) {
            u16x8 af[4], bfv[4];
            #pragma unroll
            for (int m = 0; m < 4; m++) {
                const int row = wr * 64 + m * 16 + ll;
                af[m] = *(const u16x8*)&As[row * 64 + (((kk * 4 + lg) ^ (row & 7)) * 8)];
            }
            #pragma unroll
            for (int n = 0; n < 4; n++) {
                const int row = wc * 64 + n * 16 + ll;
                bfv[n] = *(const u16x8*)&Bs[row * 64 + (((kk * 4 + lg) ^ (row & 7)) * 8)];
            }
            __builtin_amdgcn_s_setprio(1);
            #pragma unroll
            for (int m = 0; m < 4; m++)
                #pragma unroll
                for (int n = 0; n < 4; n++)
                    acc[m][n] = mfma16(af[m], bfv[n], acc[m][n]);
            __builtin_amdgcn_s_setprio(0);
        }
    }

    #pragma unroll
    for (int m = 0; m < 4; m++)
        #pragma unroll
        for (int n = 0; n < 4; n++)
            #pragma unroll
            for (int r = 0; r < 4; r++) {
                int row = m0 + wr * 64 + m * 16 + lg * 4 + r;
                int col = n0 + wc * 64 + n * 16 + ll;
                out[row * 1024 + col] = acc[m][n][r] + X[row * 1024 + col];
            }
}

// ---------------------------------------------------------------- launch
extern "C" void kernel_launch(void* const* d_in, const int* in_sizes, int n_in,
                              void* d_out, int out_size, void* d_ws, size_t ws_size,
                              hipStream_t stream) {
    const float* X  = (const float*)d_in[0];
    const float* Wq = (const float*)d_in[1];
    const float* Wk = (const float*)d_in[2];
    const float* Wv = (const float*)d_in[3];
    const float* Wo = (const float*)d_in[4];
    float* out = (float*)d_out;

    char* ws = (char*)d_ws;
    float*          pos  = (float*)(ws);                                   // 512 KB
    unsigned short* Xbf  = (unsigned short*)(ws + (512u << 10));           // 8 MB (reused as attb)
    unsigned short* Wbf  = (unsigned short*)(ws + (512u << 10) + (8u  << 20));  // 8 MB (4 stacked)
    unsigned short* qb   = (unsigned short*)(ws + (512u << 10) + (16u << 20));
    unsigned short* kb   = (unsigned short*)(ws + (512u << 10) + (24u << 20));
    unsigned short* vt   = (unsigned short*)(ws + (512u << 10) + (32u << 20));
    unsigned short* attb = Xbf;   // Xbf dead after gemm_qkv; reuse for attn output

    cvt5<<<dim3(4608), dim3(256), 0, stream>>>(X, Wq, Wk, Wv, Wo, Xbf, Wbf, pos);
    gemm_qkv<<<dim3(32, 24), dim3(256), 0, stream>>>(Xbf, Wbf, pos, qb, kb, vt);
    attn_kernel<<<dim3(16, 32), dim3(512), 0, stream>>>(qb, kb, vt, attb);
    gemm_out<<<dim3(32, 8), dim3(256), 0, stream>>>(attb, Wbf, X, out);
}

// Round 9
// 110.399 us; speedup vs baseline: 1.2084x; 1.0308x over previous
//
#include <hip/hip_runtime.h>
#include <hip/hip_bf16.h>
#include <math.h>

#define S_LEN 2048
#define DMODEL 1024
#define NHEADS 16
#define DHEAD 64
#define NBATCH 2
#define MROWS (NBATCH * S_LEN)   // 4096

typedef float f32x4 __attribute__((ext_vector_type(4)));
typedef unsigned short u16x8 __attribute__((ext_vector_type(8)));
typedef __bf16 bf16x8 __attribute__((ext_vector_type(8)));

__device__ __forceinline__ f32x4 mfma16(u16x8 a, u16x8 b, f32x4 c) {
    return __builtin_amdgcn_mfma_f32_16x16x32_bf16(
        __builtin_bit_cast(bf16x8, a), __builtin_bit_cast(bf16x8, b), c, 0, 0, 0);
}

// f32 -> bf16 round-to-nearest-even
__device__ __forceinline__ unsigned short f2bf(float f) {
    unsigned int u = __builtin_bit_cast(unsigned int, f);
    u += 0x7FFFu + ((u >> 16) & 1u);
    return (unsigned short)(u >> 16);
}

// packed f32x2 -> bf16x2 (RTNE), single HW instruction; low16 = lo
__device__ __forceinline__ unsigned int cvtpk(float lo, float hi) {
    unsigned int r;
    asm("v_cvt_pk_bf16_f32 %0, %1, %2" : "=v"(r) : "v"(lo), "v"(hi));
    return r;
}

// async global->LDS, 16B per lane; lds dest = wave-uniform base + lane*16
__device__ __forceinline__ void gl16(const void* g, void* l) {
    __builtin_amdgcn_global_load_lds(
        (const __attribute__((address_space(1))) unsigned int*)g,
        (__attribute__((address_space(3))) unsigned int*)l, 16, 0, 0);
}

// ---------------------------------------------------------------- cvt + pos
// blocks 0..2047: X. 2048..4095: Wq,Wk,Wv,Wo. 4096..4607: pos table.
__global__ __launch_bounds__(256) void cvt5(
    const float* __restrict__ X, const float* __restrict__ Wq,
    const float* __restrict__ Wk, const float* __restrict__ Wv,
    const float* __restrict__ Wo,
    unsigned short* __restrict__ Xbf, unsigned short* __restrict__ Wbf,
    float* __restrict__ pos)
{
    int b = blockIdx.x;
    if (b >= 4096) {
        int i = (b - 4096) * 256 + threadIdx.x;
        int s = i >> 6, d = i & 63;
        float theta = powf(10000.0f, (2.0f * (float)d) / 64.0f);
        float x = (float)s / theta;
        float v = (d & 1) ? cosf(x) : sinf(x);
        pos[i] = (s == 0) ? 0.0f : v;
        return;
    }
    const float* s; unsigned short* d; int t;
    if (b < 2048) { s = X; d = Xbf; t = b * 256 + threadIdx.x; }
    else {
        int z = (b - 2048) >> 9, bb = (b - 2048) & 511;
        s = (z == 0) ? Wq : (z == 1) ? Wk : (z == 2) ? Wv : Wo;
        d = Wbf + (z << 20);
        t = bb * 256 + threadIdx.x;
    }
    float4 a = *((const float4*)s + t * 2);
    float4 c = *((const float4*)s + t * 2 + 1);
    u16x8 o;
    o[0] = f2bf(a.x); o[1] = f2bf(a.y); o[2] = f2bf(a.z); o[3] = f2bf(a.w);
    o[4] = f2bf(c.x); o[5] = f2bf(c.y); o[6] = f2bf(c.z); o[7] = f2bf(c.w);
    *((u16x8*)d + t) = o;
}

// ---------------------------------------------------------------- QKV GEMM (bf16 in)
// 2-wave blocks, 128x64 tile, grid (32, 48): y>>4 selects Q/K/V, (y&15) the
// 64-col N panel. 6 blocks/CU co-resident (24KB LDS) -> deep cross-block
// interleave of the 2-phase stage/drain. Same per-wave MFMA density as 128^2.
__global__ __launch_bounds__(128) void gemm_qkv(
    const unsigned short* __restrict__ Xbf, const unsigned short* __restrict__ Wbf,
    const float* __restrict__ pos,
    unsigned short* __restrict__ qb, unsigned short* __restrict__ kb,
    unsigned short* __restrict__ vt)
{
    const int y = blockIdx.y;
    const int z = y >> 4;
    const unsigned short* __restrict__ W = Wbf + (z << 20);
    __shared__ unsigned short As[128 * 64];   // 16KB
    __shared__ unsigned short Bs[64 * 64];    // 8KB
    const int t = threadIdx.x;                // 0..127
    const int lane = t & 63;
    const int w = t >> 6;                     // 0..1
    const int m0 = blockIdx.x * 128;
    const int n0 = (y & 15) * 64;
    const int ll = lane & 15, lg = lane >> 4;
    const int r8 = lane >> 3, ch = (lane & 7) ^ r8;   // pre-swizzled source chunk

    f32x4 acc[4][4] = {};

    // running global stage pointers (advance 64 elems per K-step)
    const unsigned short* gA[8];
    const unsigned short* gB[4];
    #pragma unroll
    for (int i = 0; i < 8; i++) gA[i] = Xbf + (m0 + w * 64 + i * 8 + r8) * 1024 + ch * 8;
    #pragma unroll
    for (int i = 0; i < 4; i++) gB[i] = W + (n0 + w * 32 + i * 8 + r8) * 1024 + ch * 8;
    unsigned short* const dA = &As[(w * 64) * 64];
    unsigned short* const dB = &Bs[(w * 32) * 64];

    // hoisted LDS read pointers (swizzle: row&7 == ll&7 for all frag rows)
    const int sw0 = ((0 * 4 + lg) ^ (ll & 7)) * 16;
    const int sw1 = ((1 * 4 + lg) ^ (ll & 7)) * 16;
    const char* const pA0 = (const char*)As + (w * 64 + ll) * 128 + sw0;
    const char* const pA1 = (const char*)As + (w * 64 + ll) * 128 + sw1;
    const char* const pB0 = (const char*)Bs + ll * 128 + sw0;
    const char* const pB1 = (const char*)Bs + ll * 128 + sw1;

    for (int k0 = 0; k0 < 1024; k0 += 64) {
        __syncthreads();
        #pragma unroll
        for (int i = 0; i < 8; i++) { gl16(gA[i], dA + i * 8 * 64); gA[i] += 64; }
        #pragma unroll
        for (int i = 0; i < 4; i++) { gl16(gB[i], dB + i * 8 * 64); gB[i] += 64; }
        __syncthreads();
        u16x8 af[4], bfv[4];
        #pragma unroll
        for (int m = 0; m < 4; m++) af[m] = *(const u16x8*)(pA0 + m * 2048);
        #pragma unroll
        for (int n = 0; n < 4; n++) bfv[n] = *(const u16x8*)(pB0 + n * 2048);
        __builtin_amdgcn_s_setprio(1);
        #pragma unroll
        for (int m = 0; m < 4; m++)
            #pragma unroll
            for (int n = 0; n < 4; n++)
                acc[m][n] = mfma16(af[m], bfv[n], acc[m][n]);
        __builtin_amdgcn_s_setprio(0);
        #pragma unroll
        for (int m = 0; m < 4; m++) af[m] = *(const u16x8*)(pA1 + m * 2048);
        #pragma unroll
        for (int n = 0; n < 4; n++) bfv[n] = *(const u16x8*)(pB1 + n * 2048);
        __builtin_amdgcn_s_setprio(1);
        #pragma unroll
        for (int m = 0; m < 4; m++)
            #pragma unroll
            for (int n = 0; n < 4; n++)
                acc[m][n] = mfma16(af[m], bfv[n], acc[m][n]);
        __builtin_amdgcn_s_setprio(0);
    }

    if (z == 2) {
        // V^T: r=0..3 are s-consecutive -> one packed u64 store per (m,n)
        #pragma unroll
        for (int m = 0; m < 4; m++) {
            const int row0 = m0 + w * 64 + m * 16 + lg * 4;
            const int b = row0 >> 11, s0 = row0 & 2047;
            #pragma unroll
            for (int n = 0; n < 4; n++) {
                const int c = n0 + n * 16 + ll;      // h*64 + d
                const int h = c >> 6, d = c & 63;
                unsigned long long pk =
                    (unsigned long long)cvtpk(acc[m][n][0], acc[m][n][1]) |
                    ((unsigned long long)cvtpk(acc[m][n][2], acc[m][n][3]) << 32);
                *(unsigned long long*)&vt[(((b * NHEADS + h) * 64) + d) * S_LEN + s0] = pk;
            }
        }
    } else {
        unsigned short* const dst = (z == 0) ? qb : kb;
        #pragma unroll
        for (int m = 0; m < 4; m++) {
            #pragma unroll
            for (int n = 0; n < 4; n++) {
                #pragma unroll
                for (int r = 0; r < 4; r++) {
                    const int row = m0 + w * 64 + m * 16 + lg * 4 + r;
                    const int c = n0 + n * 16 + ll;
                    const int b = row >> 11, s = row & 2047;
                    const int h = c >> 6, d = c & 63;
                    float v = acc[m][n][r] + pos[s * 64 + d];
                    // Q: fold 1/sqrt(d_k) * log2(e) so softmax can use exp2
                    if (z == 0) v *= 0.1803368801111244f;
                    dst[(((b * NHEADS + h) * S_LEN) + s) * 64 + d] = f2bf(v);
                }
            }
        }
    }
}

// ---------------------------------------------------------------- attention
// grid (16 qt, 32 bh), 8 waves x 512 thr, QBLK=128 (wave owns 16 q-rows).
// K/V staged once per 128 q-rows, statically double-buffered (16KB KV LDS).
// nkv = 2qt+2 always even; diagonal pair peeled; waves 0-3 skip the second
// diagonal tile (fully masked for them). Fixed-shift softmax exp2(sc).
__global__ __launch_bounds__(512, 4) void attn_kernel(
    const unsigned short* __restrict__ qb,
    const unsigned short* __restrict__ kb,
    const unsigned short* __restrict__ vt,
    unsigned short* __restrict__ attnb)
{
    __shared__ unsigned short Klds[2][64 * 64];   // 8KB each
    __shared__ unsigned short Vlds[2][64 * 64];
    __shared__ unsigned short Plds[8][16 * 64];   // per-wave 2KB; total LDS = 49152

    const int bh = blockIdx.y;
    const int x = blockIdx.x;
    const int qt = (bh < 16) ? (15 - x) : x;      // pair long+short across halves

    const int lane = threadIdx.x & 63;
    const int w = threadIdx.x >> 6;               // 0..7
    const int lg = lane >> 4, ll = lane & 15;
    const int r8 = lane >> 3, ch = (lane & 7) ^ r8;

    const unsigned short* Q = qb + bh * (S_LEN * 64);
    const unsigned short* K = kb + bh * (S_LEN * 64);
    const unsigned short* V = vt + bh * (64 * S_LEN);
    const int q0 = qt * 128 + w * 16;             // wave q-base

    u16x8 qf0 = *(const u16x8*)(Q + (q0 + ll) * 64 + lg * 8);
    u16x8 qf1 = *(const u16x8*)(Q + (q0 + ll) * 64 + 32 + lg * 8);

    f32x4 o_acc[4] = {};
    float l_part = 0.0f;

    // ---- precomputed LDS byte addresses ----
    const int sw0 = ((0 * 4 + lg) ^ (ll & 7)) * 16;
    const int sw1 = ((1 * 4 + lg) ^ (ll & 7)) * 16;
    const int llb = ll * 128;
    const char* k0p0 = (const char*)&Klds[0][0] + llb + sw0;
    const char* k0p1 = (const char*)&Klds[0][0] + llb + sw1;
    const char* k1p0 = (const char*)&Klds[1][0] + llb + sw0;
    const char* k1p1 = (const char*)&Klds[1][0] + llb + sw1;
    const char* v0p0 = (const char*)&Vlds[0][0] + llb + sw0;
    const char* v0p1 = (const char*)&Vlds[0][0] + llb + sw1;
    const char* v1p0 = (const char*)&Vlds[1][0] + llb + sw0;
    const char* v1p1 = (const char*)&Vlds[1][0] + llb + sw1;
    // P write: addr = ((ll*128+lg*8) ^ (E&16)) + ((f*32) ^ (E&96)),  E=(ll&7)<<4
    const int E = (ll & 7) << 4;
    char* pwb = (char*)&Plds[w][0] + ((llb + lg * 8) ^ (E & 16));
    const int pw_o0 = 0 ^ (E & 96), pw_o1 = 32 ^ (E & 96);
    const int pw_o2 = 64 ^ (E & 96), pw_o3 = 96 ^ (E & 96);
    const char* pr0 = (const char*)&Plds[w][0] + llb + sw0;
    const char* pr1 = (const char*)&Plds[w][0] + llb + sw1;
    // staging dests (wave-uniform, 8 rows per wave) and running global srcs
    unsigned short* kd0 = &Klds[0][(w * 8) * 64];
    unsigned short* kd1 = &Klds[1][(w * 8) * 64];
    unsigned short* vd0 = &Vlds[0][(w * 8) * 64];
    unsigned short* vd1 = &Vlds[1][(w * 8) * 64];
    const unsigned short* gk = K + (w * 8 + r8) * 64 + ch * 8;
    const unsigned short* gv = V + (w * 8 + r8) * S_LEN + ch * 8;
    // diagonal thresholds: mask sc[f][r] iff f*16+r > thr (tile 2qt: thr; 2qt+1: thr-64)
    const int dthr = w * 16 + ll - lg * 4;

    auto stage2 = [&](unsigned short* kd, unsigned short* vd) {
        gl16(gk, kd);
        gl16(gv, vd);
        gk += 64 * 64;   // next KV tile: +64 K-rows
        gv += 64;        // next KV tile: +64 cols of V^T
    };

    auto tile_body = [&](const char* kp0, const char* kp1,
                         const char* vp0, const char* vp1, bool masked, int thr) {
        f32x4 sc[4] = {};
        __builtin_amdgcn_s_setprio(1);
        #pragma unroll
        for (int f = 0; f < 4; f++) {
            const u16x8 kfa = *(const u16x8*)(kp0 + f * 2048);
            sc[f] = mfma16(kfa, qf0, sc[f]);
            const u16x8 kfb = *(const u16x8*)(kp1 + f * 2048);
            sc[f] = mfma16(kfb, qf1, sc[f]);
        }
        __builtin_amdgcn_s_setprio(0);
        if (masked) {
            #pragma unroll
            for (int f = 0; f < 4; f++)
                #pragma unroll
                for (int r = 0; r < 4; r++)
                    if (f * 16 + r > thr) sc[f][r] = -1.0e9f;
        }
        float ts = 0.0f;
        #pragma unroll
        for (int f = 0; f < 4; f++)
            #pragma unroll
            for (int r = 0; r < 4; r++) {
                const float p = __builtin_amdgcn_exp2f(sc[f][r]);
                sc[f][r] = p;
                ts += p;
            }
        l_part += ts;
        *(unsigned long long*)(pwb + pw_o0) =
            (unsigned long long)cvtpk(sc[0][0], sc[0][1]) | ((unsigned long long)cvtpk(sc[0][2], sc[0][3]) << 32);
        *(unsigned long long*)(pwb + pw_o1) =
            (unsigned long long)cvtpk(sc[1][0], sc[1][1]) | ((unsigned long long)cvtpk(sc[1][2], sc[1][3]) << 32);
        *(unsigned long long*)(pwb + pw_o2) =
            (unsigned long long)cvtpk(sc[2][0], sc[2][1]) | ((unsigned long long)cvtpk(sc[2][2], sc[2][3]) << 32);
        *(unsigned long long*)(pwb + pw_o3) =
            (unsigned long long)cvtpk(sc[3][0], sc[3][1]) | ((unsigned long long)cvtpk(sc[3][2], sc[3][3]) << 32);
        const u16x8 pf0 = *(const u16x8*)pr0;
        const u16x8 pf1 = *(const u16x8*)pr1;
        __builtin_amdgcn_s_setprio(1);
        #pragma unroll
        for (int f = 0; f < 4; f++) {
            o_acc[f] = mfma16(pf0, *(const u16x8*)(vp0 + f * 2048), o_acc[f]);
            o_acc[f] = mfma16(pf1, *(const u16x8*)(vp1 + f * 2048), o_acc[f]);
        }
        __builtin_amdgcn_s_setprio(0);
    };

    stage2(kd0, vd0);   // tile 0 -> buf0

    for (int p = 0; p < qt; p++) {         // qt pairs of full (unmasked) tiles
        __syncthreads();
        stage2(kd1, vd1);                  // tile 2p+1 -> buf1
        tile_body(k0p0, k0p1, v0p0, v0p1, false, 0);
        __syncthreads();
        stage2(kd0, vd0);                  // tile 2p+2 -> buf0
        tile_body(k1p0, k1p1, v1p0, v1p1, false, 0);
    }
    // diagonal pair (tiles 2qt in buf0, 2qt+1 in buf1)
    __syncthreads();
    stage2(kd1, vd1);                      // tile 2qt+1 -> buf1
    tile_body(k0p0, k0p1, v0p0, v0p1, true, dthr);
    __syncthreads();
    if (w >= 4)                            // waves 0-3: tile 2qt+1 fully masked
        tile_body(k1p0, k1p1, v1p0, v1p1, true, dthr - 64);

    // one-time l reduction: lane (lg,ll) holds partial over its kv-subset of q=ll
    l_part += __shfl_xor(l_part, 16);
    l_part += __shfl_xor(l_part, 32);

    const int bb = bh >> 4, h = bh & 15;
    float lr0 = 1.0f / __shfl(l_part, lg * 4 + 0);
    float lr1 = 1.0f / __shfl(l_part, lg * 4 + 1);
    float lr2 = 1.0f / __shfl(l_part, lg * 4 + 2);
    float lr3 = 1.0f / __shfl(l_part, lg * 4 + 3);
    #pragma unroll
    for (int f = 0; f < 4; f++) {
        const int colbase = h * 64 + f * 16 + ll;
        attnb[(bb * S_LEN + q0 + lg * 4 + 0) * DMODEL + colbase] = f2bf(o_acc[f][0] * lr0);
        attnb[(bb * S_LEN + q0 + lg * 4 + 1) * DMODEL + colbase] = f2bf(o_acc[f][1] * lr1);
        attnb[(bb * S_LEN + q0 + lg * 4 + 2) * DMODEL + colbase] = f2bf(o_acc[f][2] * lr2);
        attnb[(bb * S_LEN + q0 + lg * 4 + 3) * DMODEL + colbase] = f2bf(o_acc[f][3] * lr3);
    }
}

// ---------------------------------------------------------------- out GEMM
// out = attn @ Wo^T + X. A bf16, B = Wbf+3M, out f32. r5 structure + hoisted
// stage/frag pointers.
__global__ __launch_bounds__(256) void gemm_out(
    const unsigned short* __restrict__ Abf,
    const unsigned short* __restrict__ Wbf,
    const float* __restrict__ X,
    float* __restrict__ out)
{
    const unsigned short* __restrict__ W = Wbf + (3u << 20);
    __shared__ unsigned short As[128 * 64];
    __shared__ unsigned short Bs[128 * 64];
    const int t = threadIdx.x;
    const int lane = t & 63;
    const int w = t >> 6, wr = w >> 1, wc = w & 1;
    const int m0 = blockIdx.x * 128;
    const int n0 = blockIdx.y * 128;
    const int ll = lane & 15, lg = lane >> 4;
    const int r8 = lane >> 3, ch = (lane & 7) ^ r8;

    f32x4 acc[4][4] = {};

    const unsigned short* gA[4];
    const unsigned short* gB[4];
    #pragma unroll
    for (int c = 0; c < 4; c++) {
        gA[c] = Abf + (m0 + c * 32 + w * 8 + r8) * 1024 + ch * 8;
        gB[c] = W + (n0 + c * 32 + w * 8 + r8) * 1024 + ch * 8;
    }
    const int sw0 = ((0 * 4 + lg) ^ (ll & 7)) * 16;
    const int sw1 = ((1 * 4 + lg) ^ (ll & 7)) * 16;
    const char* const pA0 = (const char*)As + (wr * 64 + ll) * 128 + sw0;
    const char* const pA1 = (const char*)As + (wr * 64 + ll) * 128 + sw1;
    const char* const pB0 = (const char*)Bs + (wc * 64 + ll) * 128 + sw0;
    const char* const pB1 = (const char*)Bs + (wc * 64 + ll) * 128 + sw1;

    for (int k0 = 0; k0 < 1024; k0 += 64) {
        __syncthreads();
        #pragma unroll
        for (int c = 0; c < 4; c++) {
            gl16(gA[c], &As[(c * 32 + w * 8) * 64]); gA[c] += 64;
            gl16(gB[c], &Bs[(c * 32 + w * 8) * 64]); gB[c] += 64;
        }
        __syncthreads();
        u16x8 af[4], bfv[4];
        #pragma unroll
        for (int m = 0; m < 4; m++) af[m] = *(const u16x8*)(pA0 + m * 2048);
        #pragma unroll
        for (int n = 0; n < 4; n++) bfv[n] = *(const u16x8*)(pB0 + n * 2048);
        __builtin_amdgcn_s_setprio(1);
        #pragma unroll
        for (int m = 0; m < 4; m++)
            #pragma unroll
            for (int n = 0; n < 4; n++)
                acc[m][n] = mfma16(af[m], bfv[n], acc[m][n]);
        __builtin_amdgcn_s_setprio(0);
        #pragma unroll
        for (int m = 0; m < 4; m++) af[m] = *(const u16x8*)(pA1 + m * 2048);
        #pragma unroll
        for (int n = 0; n < 4; n++) bfv[n] = *(const u16x8*)(pB1 + n * 2048);
        __builtin_amdgcn_s_setprio(1);
        #pragma unroll
        for (int m = 0; m < 4; m++)
            #pragma unroll
            for (int n = 0; n < 4; n++)
                acc[m][n] = mfma16(af[m], bfv[n], acc[m][n]);
        __builtin_amdgcn_s_setprio(0);
    }

    #pragma unroll
    for (int m = 0; m < 4; m++)
        #pragma unroll
        for (int n = 0; n < 4; n++)
            #pragma unroll
            for (int r = 0; r < 4; r++) {
                int row = m0 + wr * 64 + m * 16 + lg * 4 + r;
                int col = n0 + wc * 64 + n * 16 + ll;
                out[row * 1024 + col] = acc[m][n][r] + X[row * 1024 + col];
            }
}

// ---------------------------------------------------------------- launch
extern "C" void kernel_launch(void* const* d_in, const int* in_sizes, int n_in,
                              void* d_out, int out_size, void* d_ws, size_t ws_size,
                              hipStream_t stream) {
    const float* X  = (const float*)d_in[0];
    const float* Wq = (const float*)d_in[1];
    const float* Wk = (const float*)d_in[2];
    const float* Wv = (const float*)d_in[3];
    const float* Wo = (const float*)d_in[4];
    float* out = (float*)d_out;

    char* ws = (char*)d_ws;
    float*          pos  = (float*)(ws);                                   // 512 KB
    unsigned short* Xbf  = (unsigned short*)(ws + (512u << 10));           // 8 MB (reused as attb)
    unsigned short* Wbf  = (unsigned short*)(ws + (512u << 10) + (8u  << 20));  // 8 MB (4 stacked)
    unsigned short* qb   = (unsigned short*)(ws + (512u << 10) + (16u << 20));
    unsigned short* kb   = (unsigned short*)(ws + (512u << 10) + (24u << 20));
    unsigned short* vt   = (unsigned short*)(ws + (512u << 10) + (32u << 20));
    unsigned short* attb = Xbf;   // Xbf dead after gemm_qkv; reuse for attn output

    cvt5<<<dim3(4608), dim3(256), 0, stream>>>(X, Wq, Wk, Wv, Wo, Xbf, Wbf, pos);
    gemm_qkv<<<dim3(32, 48), dim3(128), 0, stream>>>(Xbf, Wbf, pos, qb, kb, vt);
    attn_kernel<<<dim3(16, 32), dim3(512), 0, stream>>>(qb, kb, vt, attb);
    gemm_out<<<dim3(32, 8), dim3(256), 0, stream>>>(attb, Wbf, X, out);
}

// Round 10
// 102.382 us; speedup vs baseline: 1.3030x; 1.0783x over previous
//
#include <hip/hip_runtime.h>
#include <hip/hip_bf16.h>
#include <math.h>

#define S_LEN 2048
#define DMODEL 1024
#define NHEADS 16
#define DHEAD 64
#define NBATCH 2
#define MROWS (NBATCH * S_LEN)   // 4096

typedef float f32x4 __attribute__((ext_vector_type(4)));
typedef unsigned short u16x8 __attribute__((ext_vector_type(8)));
typedef __bf16 bf16x8 __attribute__((ext_vector_type(8)));

__device__ __forceinline__ f32x4 mfma16(u16x8 a, u16x8 b, f32x4 c) {
    return __builtin_amdgcn_mfma_f32_16x16x32_bf16(
        __builtin_bit_cast(bf16x8, a), __builtin_bit_cast(bf16x8, b), c, 0, 0, 0);
}

// f32 -> bf16 round-to-nearest-even
__device__ __forceinline__ unsigned short f2bf(float f) {
    unsigned int u = __builtin_bit_cast(unsigned int, f);
    u += 0x7FFFu + ((u >> 16) & 1u);
    return (unsigned short)(u >> 16);
}

// packed f32x2 -> bf16x2 (RTNE), single HW instruction; low16 = lo
__device__ __forceinline__ unsigned int cvtpk(float lo, float hi) {
    unsigned int r;
    asm("v_cvt_pk_bf16_f32 %0, %1, %2" : "=v"(r) : "v"(lo), "v"(hi));
    return r;
}

// async global->LDS, 16B per lane; lds dest = wave-uniform base + lane*16
__device__ __forceinline__ void gl16(const void* g, void* l) {
    __builtin_amdgcn_global_load_lds(
        (const __attribute__((address_space(1))) unsigned int*)g,
        (__attribute__((address_space(3))) unsigned int*)l, 16, 0, 0);
}

// counted-vmcnt barrier: wait N outstanding vmem, then raw barrier.
// sched_barrier(0) fences both sides so no ds_read/gl16 migrates across.
#define PIPE_BAR_12() do { \
    asm volatile("s_waitcnt vmcnt(12)" ::: "memory"); \
    __builtin_amdgcn_sched_barrier(0); \
    __builtin_amdgcn_s_barrier(); \
    __builtin_amdgcn_sched_barrier(0); } while (0)
#define PIPE_BAR_0() do { \
    asm volatile("s_waitcnt vmcnt(0)" ::: "memory"); \
    __builtin_amdgcn_sched_barrier(0); \
    __builtin_amdgcn_s_barrier(); \
    __builtin_amdgcn_sched_barrier(0); } while (0)

// ---------------------------------------------------------------- cvt + pos
// blocks 0..2047: X. 2048..4095: Wq,Wk,Wv,Wo. 4096..4607: pos table.
__global__ __launch_bounds__(256) void cvt5(
    const float* __restrict__ X, const float* __restrict__ Wq,
    const float* __restrict__ Wk, const float* __restrict__ Wv,
    const float* __restrict__ Wo,
    unsigned short* __restrict__ Xbf, unsigned short* __restrict__ Wbf,
    float* __restrict__ pos)
{
    int b = blockIdx.x;
    if (b >= 4096) {
        int i = (b - 4096) * 256 + threadIdx.x;
        int s = i >> 6, d = i & 63;
        float theta = powf(10000.0f, (2.0f * (float)d) / 64.0f);
        float x = (float)s / theta;
        float v = (d & 1) ? cosf(x) : sinf(x);
        pos[i] = (s == 0) ? 0.0f : v;
        return;
    }
    const float* s; unsigned short* d; int t;
    if (b < 2048) { s = X; d = Xbf; t = b * 256 + threadIdx.x; }
    else {
        int z = (b - 2048) >> 9, bb = (b - 2048) & 511;
        s = (z == 0) ? Wq : (z == 1) ? Wk : (z == 2) ? Wv : Wo;
        d = Wbf + (z << 20);
        t = bb * 256 + threadIdx.x;
    }
    float4 a = *((const float4*)s + t * 2);
    float4 c = *((const float4*)s + t * 2 + 1);
    u16x8 o;
    o[0] = f2bf(a.x); o[1] = f2bf(a.y); o[2] = f2bf(a.z); o[3] = f2bf(a.w);
    o[4] = f2bf(c.x); o[5] = f2bf(c.y); o[6] = f2bf(c.z); o[7] = f2bf(c.w);
    *((u16x8*)d + t) = o;
}

// ---------------------------------------------------------------- QKV GEMM (bf16 in)
// 2-wave blocks, 128x64 tile, grid (32, 48): y>>4 selects Q/K/V, (y&15) the
// 64-col N panel. 3-buffer LDS pipeline with counted vmcnt(12) + raw s_barrier
// (no vmcnt(0) drain in main loop). Buffer b: A rows [0..128), B rows at +8192.
__global__ __launch_bounds__(128) void gemm_qkv(
    const unsigned short* __restrict__ Xbf, const unsigned short* __restrict__ Wbf,
    const float* __restrict__ pos,
    unsigned short* __restrict__ qb, unsigned short* __restrict__ kb,
    unsigned short* __restrict__ vt)
{
    const int y = blockIdx.y;
    const int z = y >> 4;
    const unsigned short* __restrict__ W = Wbf + (z << 20);
    __shared__ unsigned short L[3][192 * 64];   // 24KB x 3 = 72KB
    const int t = threadIdx.x;                  // 0..127
    const int lane = t & 63;
    const int w = t >> 6;                       // 0..1
    const int m0 = blockIdx.x * 128;
    const int n0 = (y & 15) * 64;
    const int ll = lane & 15, lg = lane >> 4;
    const int r8 = lane >> 3, ch = (lane & 7) ^ r8;   // pre-swizzled source chunk

    f32x4 acc[4][4] = {};

    // running global stage pointers (advance 64 elems per stage call)
    const unsigned short* gA[8];
    const unsigned short* gB[4];
    #pragma unroll
    for (int i = 0; i < 8; i++) gA[i] = Xbf + (m0 + w * 64 + i * 8 + r8) * 1024 + ch * 8;
    #pragma unroll
    for (int i = 0; i < 4; i++) gB[i] = W + (n0 + w * 32 + i * 8 + r8) * 1024 + ch * 8;

    const int sw0 = ((0 * 4 + lg) ^ (ll & 7)) * 16;
    const int sw1 = ((1 * 4 + lg) ^ (ll & 7)) * 16;

    // 12 gl16 per wave per call; advances gA/gB
    auto stage = [&](unsigned short* Lb) {
        unsigned short* const dA = Lb + (w * 64) * 64;
        unsigned short* const dB = Lb + 128 * 64 + (w * 32) * 64;
        #pragma unroll
        for (int i = 0; i < 8; i++) { gl16(gA[i], dA + i * 8 * 64); gA[i] += 64; }
        #pragma unroll
        for (int i = 0; i < 4; i++) { gl16(gB[i], dB + i * 8 * 64); gB[i] += 64; }
    };
    auto compute = [&](const unsigned short* Lb) {
        const char* const pA0 = (const char*)Lb + (w * 64 + ll) * 128 + sw0;
        const char* const pA1 = (const char*)Lb + (w * 64 + ll) * 128 + sw1;
        const char* const pB0 = (const char*)Lb + 16384 + ll * 128 + sw0;
        const char* const pB1 = (const char*)Lb + 16384 + ll * 128 + sw1;
        u16x8 af[4], bfv[4];
        #pragma unroll
        for (int m = 0; m < 4; m++) af[m] = *(const u16x8*)(pA0 + m * 2048);
        #pragma unroll
        for (int n = 0; n < 4; n++) bfv[n] = *(const u16x8*)(pB0 + n * 2048);
        __builtin_amdgcn_s_setprio(1);
        #pragma unroll
        for (int m = 0; m < 4; m++)
            #pragma unroll
            for (int n = 0; n < 4; n++)
                acc[m][n] = mfma16(af[m], bfv[n], acc[m][n]);
        __builtin_amdgcn_s_setprio(0);
        #pragma unroll
        for (int m = 0; m < 4; m++) af[m] = *(const u16x8*)(pA1 + m * 2048);
        #pragma unroll
        for (int n = 0; n < 4; n++) bfv[n] = *(const u16x8*)(pB1 + n * 2048);
        __builtin_amdgcn_s_setprio(1);
        #pragma unroll
        for (int m = 0; m < 4; m++)
            #pragma unroll
            for (int n = 0; n < 4; n++)
                acc[m][n] = mfma16(af[m], bfv[n], acc[m][n]);
        __builtin_amdgcn_s_setprio(0);
    };

    // prologue: stage t0->L0, t1->L1; wait t0 (t1's 12 stay in flight)
    stage(L[0]);
    stage(L[1]);
    PIPE_BAR_12();
    // steady state: t = 0..11 (stage t+2, compute t, wait t+1)
    for (int tt = 0; tt < 4; tt++) {
        stage(L[2]); compute(L[0]); PIPE_BAR_12();
        stage(L[0]); compute(L[1]); PIPE_BAR_12();
        stage(L[1]); compute(L[2]); PIPE_BAR_12();
    }
    // t=12: stage t14->L2, compute L0 ; t=13: stage t15->L0, compute L1
    stage(L[2]); compute(L[0]); PIPE_BAR_12();
    stage(L[0]); compute(L[1]); PIPE_BAR_12();
    // t=14: compute L2, full drain ; t=15: compute L0
    compute(L[2]); PIPE_BAR_0();
    compute(L[0]);

    if (z == 2) {
        // V^T: r=0..3 are s-consecutive -> one packed u64 store per (m,n)
        #pragma unroll
        for (int m = 0; m < 4; m++) {
            const int row0 = m0 + w * 64 + m * 16 + lg * 4;
            const int b = row0 >> 11, s0 = row0 & 2047;
            #pragma unroll
            for (int n = 0; n < 4; n++) {
                const int c = n0 + n * 16 + ll;      // h*64 + d
                const int h = c >> 6, d = c & 63;
                unsigned long long pk =
                    (unsigned long long)cvtpk(acc[m][n][0], acc[m][n][1]) |
                    ((unsigned long long)cvtpk(acc[m][n][2], acc[m][n][3]) << 32);
                *(unsigned long long*)&vt[(((b * NHEADS + h) * 64) + d) * S_LEN + s0] = pk;
            }
        }
    } else {
        unsigned short* const dst = (z == 0) ? qb : kb;
        #pragma unroll
        for (int m = 0; m < 4; m++) {
            #pragma unroll
            for (int n = 0; n < 4; n++) {
                #pragma unroll
                for (int r = 0; r < 4; r++) {
                    const int row = m0 + w * 64 + m * 16 + lg * 4 + r;
                    const int c = n0 + n * 16 + ll;
                    const int b = row >> 11, s = row & 2047;
                    const int h = c >> 6, d = c & 63;
                    float v = acc[m][n][r] + pos[s * 64 + d];
                    // Q: fold 1/sqrt(d_k) * log2(e) so softmax can use exp2
                    if (z == 0) v *= 0.1803368801111244f;
                    dst[(((b * NHEADS + h) * S_LEN) + s) * 64 + d] = f2bf(v);
                }
            }
        }
    }
}

// ---------------------------------------------------------------- attention
// grid (16 qt, 32 bh), 8 waves x 512 thr, QBLK=128 (wave owns 16 q-rows).
// K/V staged once per 128 q-rows, statically double-buffered (16KB KV LDS).
// nkv = 2qt+2 always even; diagonal pair peeled; waves 0-3 skip the second
// diagonal tile (fully masked for them). Fixed-shift softmax exp2(sc).
__global__ __launch_bounds__(512, 4) void attn_kernel(
    const unsigned short* __restrict__ qb,
    const unsigned short* __restrict__ kb,
    const unsigned short* __restrict__ vt,
    unsigned short* __restrict__ attnb)
{
    __shared__ unsigned short Klds[2][64 * 64];   // 8KB each
    __shared__ unsigned short Vlds[2][64 * 64];
    __shared__ unsigned short Plds[8][16 * 64];   // per-wave 2KB; total LDS = 49152

    const int bh = blockIdx.y;
    const int x = blockIdx.x;
    const int qt = (bh < 16) ? (15 - x) : x;      // pair long+short across halves

    const int lane = threadIdx.x & 63;
    const int w = threadIdx.x >> 6;               // 0..7
    const int lg = lane >> 4, ll = lane & 15;
    const int r8 = lane >> 3, ch = (lane & 7) ^ r8;

    const unsigned short* Q = qb + bh * (S_LEN * 64);
    const unsigned short* K = kb + bh * (S_LEN * 64);
    const unsigned short* V = vt + bh * (64 * S_LEN);
    const int q0 = qt * 128 + w * 16;             // wave q-base

    u16x8 qf0 = *(const u16x8*)(Q + (q0 + ll) * 64 + lg * 8);
    u16x8 qf1 = *(const u16x8*)(Q + (q0 + ll) * 64 + 32 + lg * 8);

    f32x4 o_acc[4] = {};
    float l_part = 0.0f;

    // ---- precomputed LDS byte addresses ----
    const int sw0 = ((0 * 4 + lg) ^ (ll & 7)) * 16;
    const int sw1 = ((1 * 4 + lg) ^ (ll & 7)) * 16;
    const int llb = ll * 128;
    const char* k0p0 = (const char*)&Klds[0][0] + llb + sw0;
    const char* k0p1 = (const char*)&Klds[0][0] + llb + sw1;
    const char* k1p0 = (const char*)&Klds[1][0] + llb + sw0;
    const char* k1p1 = (const char*)&Klds[1][0] + llb + sw1;
    const char* v0p0 = (const char*)&Vlds[0][0] + llb + sw0;
    const char* v0p1 = (const char*)&Vlds[0][0] + llb + sw1;
    const char* v1p0 = (const char*)&Vlds[1][0] + llb + sw0;
    const char* v1p1 = (const char*)&Vlds[1][0] + llb + sw1;
    // P write: addr = ((ll*128+lg*8) ^ (E&16)) + ((f*32) ^ (E&96)),  E=(ll&7)<<4
    const int E = (ll & 7) << 4;
    char* pwb = (char*)&Plds[w][0] + ((llb + lg * 8) ^ (E & 16));
    const int pw_o0 = 0 ^ (E & 96), pw_o1 = 32 ^ (E & 96);
    const int pw_o2 = 64 ^ (E & 96), pw_o3 = 96 ^ (E & 96);
    const char* pr0 = (const char*)&Plds[w][0] + llb + sw0;
    const char* pr1 = (const char*)&Plds[w][0] + llb + sw1;
    // staging dests (wave-uniform, 8 rows per wave) and running global srcs
    unsigned short* kd0 = &Klds[0][(w * 8) * 64];
    unsigned short* kd1 = &Klds[1][(w * 8) * 64];
    unsigned short* vd0 = &Vlds[0][(w * 8) * 64];
    unsigned short* vd1 = &Vlds[1][(w * 8) * 64];
    const unsigned short* gk = K + (w * 8 + r8) * 64 + ch * 8;
    const unsigned short* gv = V + (w * 8 + r8) * S_LEN + ch * 8;
    // diagonal thresholds: mask sc[f][r] iff f*16+r > thr (tile 2qt: thr; 2qt+1: thr-64)
    const int dthr = w * 16 + ll - lg * 4;

    auto stage2 = [&](unsigned short* kd, unsigned short* vd) {
        gl16(gk, kd);
        gl16(gv, vd);
        gk += 64 * 64;   // next KV tile: +64 K-rows
        gv += 64;        // next KV tile: +64 cols of V^T
    };

    auto tile_body = [&](const char* kp0, const char* kp1,
                         const char* vp0, const char* vp1, bool masked, int thr) {
        f32x4 sc[4] = {};
        __builtin_amdgcn_s_setprio(1);
        #pragma unroll
        for (int f = 0; f < 4; f++) {
            const u16x8 kfa = *(const u16x8*)(kp0 + f * 2048);
            sc[f] = mfma16(kfa, qf0, sc[f]);
            const u16x8 kfb = *(const u16x8*)(kp1 + f * 2048);
            sc[f] = mfma16(kfb, qf1, sc[f]);
        }
        __builtin_amdgcn_s_setprio(0);
        if (masked) {
            #pragma unroll
            for (int f = 0; f < 4; f++)
                #pragma unroll
                for (int r = 0; r < 4; r++)
                    if (f * 16 + r > thr) sc[f][r] = -1.0e9f;
        }
        float ts = 0.0f;
        #pragma unroll
        for (int f = 0; f < 4; f++)
            #pragma unroll
            for (int r = 0; r < 4; r++) {
                const float p = __builtin_amdgcn_exp2f(sc[f][r]);
                sc[f][r] = p;
                ts += p;
            }
        l_part += ts;
        *(unsigned long long*)(pwb + pw_o0) =
            (unsigned long long)cvtpk(sc[0][0], sc[0][1]) | ((unsigned long long)cvtpk(sc[0][2], sc[0][3]) << 32);
        *(unsigned long long*)(pwb + pw_o1) =
            (unsigned long long)cvtpk(sc[1][0], sc[1][1]) | ((unsigned long long)cvtpk(sc[1][2], sc[1][3]) << 32);
        *(unsigned long long*)(pwb + pw_o2) =
            (unsigned long long)cvtpk(sc[2][0], sc[2][1]) | ((unsigned long long)cvtpk(sc[2][2], sc[2][3]) << 32);
        *(unsigned long long*)(pwb + pw_o3) =
            (unsigned long long)cvtpk(sc[3][0], sc[3][1]) | ((unsigned long long)cvtpk(sc[3][2], sc[3][3]) << 32);
        const u16x8 pf0 = *(const u16x8*)pr0;
        const u16x8 pf1 = *(const u16x8*)pr1;
        __builtin_amdgcn_s_setprio(1);
        #pragma unroll
        for (int f = 0; f < 4; f++) {
            o_acc[f] = mfma16(pf0, *(const u16x8*)(vp0 + f * 2048), o_acc[f]);
            o_acc[f] = mfma16(pf1, *(const u16x8*)(vp1 + f * 2048), o_acc[f]);
        }
        __builtin_amdgcn_s_setprio(0);
    };

    stage2(kd0, vd0);   // tile 0 -> buf0

    for (int p = 0; p < qt; p++) {         // qt pairs of full (unmasked) tiles
        __syncthreads();
        stage2(kd1, vd1);                  // tile 2p+1 -> buf1
        tile_body(k0p0, k0p1, v0p0, v0p1, false, 0);
        __syncthreads();
        stage2(kd0, vd0);                  // tile 2p+2 -> buf0
        tile_body(k1p0, k1p1, v1p0, v1p1, false, 0);
    }
    // diagonal pair (tiles 2qt in buf0, 2qt+1 in buf1)
    __syncthreads();
    stage2(kd1, vd1);                      // tile 2qt+1 -> buf1
    tile_body(k0p0, k0p1, v0p0, v0p1, true, dthr);
    __syncthreads();
    if (w >= 4)                            // waves 0-3: tile 2qt+1 fully masked
        tile_body(k1p0, k1p1, v1p0, v1p1, true, dthr - 64);

    // one-time l reduction: lane (lg,ll) holds partial over its kv-subset of q=ll
    l_part += __shfl_xor(l_part, 16);
    l_part += __shfl_xor(l_part, 32);

    const int bb = bh >> 4, h = bh & 15;
    float lr0 = 1.0f / __shfl(l_part, lg * 4 + 0);
    float lr1 = 1.0f / __shfl(l_part, lg * 4 + 1);
    float lr2 = 1.0f / __shfl(l_part, lg * 4 + 2);
    float lr3 = 1.0f / __shfl(l_part, lg * 4 + 3);
    #pragma unroll
    for (int f = 0; f < 4; f++) {
        const int colbase = h * 64 + f * 16 + ll;
        attnb[(bb * S_LEN + q0 + lg * 4 + 0) * DMODEL + colbase] = f2bf(o_acc[f][0] * lr0);
        attnb[(bb * S_LEN + q0 + lg * 4 + 1) * DMODEL + colbase] = f2bf(o_acc[f][1] * lr1);
        attnb[(bb * S_LEN + q0 + lg * 4 + 2) * DMODEL + colbase] = f2bf(o_acc[f][2] * lr2);
        attnb[(bb * S_LEN + q0 + lg * 4 + 3) * DMODEL + colbase] = f2bf(o_acc[f][3] * lr3);
    }
}

// ---------------------------------------------------------------- out GEMM
// out = attn @ Wo^T + X. Same 3-buffer counted-vmcnt pipeline, 2-wave 128x64,
// grid (32, 16).
__global__ __launch_bounds__(128) void gemm_out(
    const unsigned short* __restrict__ Abf,
    const unsigned short* __restrict__ Wbf,
    const float* __restrict__ X,
    float* __restrict__ out)
{
    const unsigned short* __restrict__ W = Wbf + (3u << 20);
    __shared__ unsigned short L[3][192 * 64];   // 72KB
    const int t = threadIdx.x;
    const int lane = t & 63;
    const int w = t >> 6;
    const int m0 = blockIdx.x * 128;
    const int n0 = blockIdx.y * 64;
    const int ll = lane & 15, lg = lane >> 4;
    const int r8 = lane >> 3, ch = (lane & 7) ^ r8;

    f32x4 acc[4][4] = {};

    const unsigned short* gA[8];
    const unsigned short* gB[4];
    #pragma unroll
    for (int i = 0; i < 8; i++) gA[i] = Abf + (m0 + w * 64 + i * 8 + r8) * 1024 + ch * 8;
    #pragma unroll
    for (int i = 0; i < 4; i++) gB[i] = W + (n0 + w * 32 + i * 8 + r8) * 1024 + ch * 8;

    const int sw0 = ((0 * 4 + lg) ^ (ll & 7)) * 16;
    const int sw1 = ((1 * 4 + lg) ^ (ll & 7)) * 16;

    auto stage = [&](unsigned short* Lb) {
        unsigned short* const dA = Lb + (w * 64) * 64;
        unsigned short* const dB = Lb + 128 * 64 + (w * 32) * 64;
        #pragma unroll
        for (int i = 0; i < 8; i++) { gl16(gA[i], dA + i * 8 * 64); gA[i] += 64; }
        #pragma unroll
        for (int i = 0; i < 4; i++) { gl16(gB[i], dB + i * 8 * 64); gB[i] += 64; }
    };
    auto compute = [&](const unsigned short* Lb) {
        const char* const pA0 = (const char*)Lb + (w * 64 + ll) * 128 + sw0;
        const char* const pA1 = (const char*)Lb + (w * 64 + ll) * 128 + sw1;
        const char* const pB0 = (const char*)Lb + 16384 + ll * 128 + sw0;
        const char* const pB1 = (const char*)Lb + 16384 + ll * 128 + sw1;
        u16x8 af[4], bfv[4];
        #pragma unroll
        for (int m = 0; m < 4; m++) af[m] = *(const u16x8*)(pA0 + m * 2048);
        #pragma unroll
        for (int n = 0; n < 4; n++) bfv[n] = *(const u16x8*)(pB0 + n * 2048);
        __builtin_amdgcn_s_setprio(1);
        #pragma unroll
        for (int m = 0; m < 4; m++)
            #pragma unroll
            for (int n = 0; n < 4; n++)
                acc[m][n] = mfma16(af[m], bfv[n], acc[m][n]);
        __builtin_amdgcn_s_setprio(0);
        #pragma unroll
        for (int m = 0; m < 4; m++) af[m] = *(const u16x8*)(pA1 + m * 2048);
        #pragma unroll
        for (int n = 0; n < 4; n++) bfv[n] = *(const u16x8*)(pB1 + n * 2048);
        __builtin_amdgcn_s_setprio(1);
        #pragma unroll
        for (int m = 0; m < 4; m++)
            #pragma unroll
            for (int n = 0; n < 4; n++)
                acc[m][n] = mfma16(af[m], bfv[n], acc[m][n]);
        __builtin_amdgcn_s_setprio(0);
    };

    stage(L[0]);
    stage(L[1]);
    PIPE_BAR_12();
    for (int tt = 0; tt < 4; tt++) {
        stage(L[2]); compute(L[0]); PIPE_BAR_12();
        stage(L[0]); compute(L[1]); PIPE_BAR_12();
        stage(L[1]); compute(L[2]); PIPE_BAR_12();
    }
    stage(L[2]); compute(L[0]); PIPE_BAR_12();
    stage(L[0]); compute(L[1]); PIPE_BAR_12();
    compute(L[2]); PIPE_BAR_0();
    compute(L[0]);

    #pragma unroll
    for (int m = 0; m < 4; m++)
        #pragma unroll
        for (int n = 0; n < 4; n++)
            #pragma unroll
            for (int r = 0; r < 4; r++) {
                const int row = m0 + w * 64 + m * 16 + lg * 4 + r;
                const int col = n0 + n * 16 + ll;
                out[row * 1024 + col] = acc[m][n][r] + X[row * 1024 + col];
            }
}

// ---------------------------------------------------------------- launch
extern "C" void kernel_launch(void* const* d_in, const int* in_sizes, int n_in,
                              void* d_out, int out_size, void* d_ws, size_t ws_size,
                              hipStream_t stream) {
    const float* X  = (const float*)d_in[0];
    const float* Wq = (const float*)d_in[1];
    const float* Wk = (const float*)d_in[2];
    const float* Wv = (const float*)d_in[3];
    const float* Wo = (const float*)d_in[4];
    float* out = (float*)d_out;

    char* ws = (char*)d_ws;
    float*          pos  = (float*)(ws);                                   // 512 KB
    unsigned short* Xbf  = (unsigned short*)(ws + (512u << 10));           // 8 MB (reused as attb)
    unsigned short* Wbf  = (unsigned short*)(ws + (512u << 10) + (8u  << 20));  // 8 MB (4 stacked)
    unsigned short* qb   = (unsigned short*)(ws + (512u << 10) + (16u << 20));
    unsigned short* kb   = (unsigned short*)(ws + (512u << 10) + (24u << 20));
    unsigned short* vt   = (unsigned short*)(ws + (512u << 10) + (32u << 20));
    unsigned short* attb = Xbf;   // Xbf dead after gemm_qkv; reuse for attn output

    cvt5<<<dim3(4608), dim3(256), 0, stream>>>(X, Wq, Wk, Wv, Wo, Xbf, Wbf, pos);
    gemm_qkv<<<dim3(32, 48), dim3(128), 0, stream>>>(Xbf, Wbf, pos, qb, kb, vt);
    attn_kernel<<<dim3(16, 32), dim3(512), 0, stream>>>(qb, kb, vt, attb);
    gemm_out<<<dim3(32, 16), dim3(128), 0, stream>>>(attb, Wbf, X, out);
}

// Round 11
// 98.606 us; speedup vs baseline: 1.3529x; 1.0383x over previous
//
#include <hip/hip_runtime.h>
#include <hip/hip_bf16.h>
#include <math.h>

#define S_LEN 2048
#define DMODEL 1024
#define NHEADS 16
#define DHEAD 64
#define NBATCH 2
#define MROWS (NBATCH * S_LEN)   // 4096

typedef float f32x4 __attribute__((ext_vector_type(4)));
typedef unsigned short u16x8 __attribute__((ext_vector_type(8)));
typedef __bf16 bf16x8 __attribute__((ext_vector_type(8)));

__device__ __forceinline__ f32x4 mfma16(u16x8 a, u16x8 b, f32x4 c) {
    return __builtin_amdgcn_mfma_f32_16x16x32_bf16(
        __builtin_bit_cast(bf16x8, a), __builtin_bit_cast(bf16x8, b), c, 0, 0, 0);
}

// f32 -> bf16 round-to-nearest-even
__device__ __forceinline__ unsigned short f2bf(float f) {
    unsigned int u = __builtin_bit_cast(unsigned int, f);
    u += 0x7FFFu + ((u >> 16) & 1u);
    return (unsigned short)(u >> 16);
}

// packed f32x2 -> bf16x2 (RTNE), single HW instruction; low16 = lo
__device__ __forceinline__ unsigned int cvtpk(float lo, float hi) {
    unsigned int r;
    asm("v_cvt_pk_bf16_f32 %0, %1, %2" : "=v"(r) : "v"(lo), "v"(hi));
    return r;
}

// async global->LDS, 16B per lane; lds dest = wave-uniform base + lane*16
__device__ __forceinline__ void gl16(const void* g, void* l) {
    __builtin_amdgcn_global_load_lds(
        (const __attribute__((address_space(1))) unsigned int*)g,
        (__attribute__((address_space(3))) unsigned int*)l, 16, 0, 0);
}

// counted-vmcnt barrier: wait N outstanding vmem, then raw barrier.
#define PIPE_BAR_12() do { \
    asm volatile("s_waitcnt vmcnt(12)" ::: "memory"); \
    __builtin_amdgcn_sched_barrier(0); \
    __builtin_amdgcn_s_barrier(); \
    __builtin_amdgcn_sched_barrier(0); } while (0)
#define PIPE_BAR_0() do { \
    asm volatile("s_waitcnt vmcnt(0)" ::: "memory"); \
    __builtin_amdgcn_sched_barrier(0); \
    __builtin_amdgcn_s_barrier(); \
    __builtin_amdgcn_sched_barrier(0); } while (0)

// ---------------------------------------------------------------- cvt + pos
// blocks 0..2047: X. 2048..4095: Wq,Wk,Wv,Wo. 4096..4607: pos table.
__global__ __launch_bounds__(256) void cvt5(
    const float* __restrict__ X, const float* __restrict__ Wq,
    const float* __restrict__ Wk, const float* __restrict__ Wv,
    const float* __restrict__ Wo,
    unsigned short* __restrict__ Xbf, unsigned short* __restrict__ Wbf,
    float* __restrict__ pos)
{
    int b = blockIdx.x;
    if (b >= 4096) {
        int i = (b - 4096) * 256 + threadIdx.x;
        int s = i >> 6, d = i & 63;
        float theta = powf(10000.0f, (2.0f * (float)d) / 64.0f);
        float x = (float)s / theta;
        float v = (d & 1) ? cosf(x) : sinf(x);
        pos[i] = (s == 0) ? 0.0f : v;
        return;
    }
    const float* s; unsigned short* d; int t;
    if (b < 2048) { s = X; d = Xbf; t = b * 256 + threadIdx.x; }
    else {
        int z = (b - 2048) >> 9, bb = (b - 2048) & 511;
        s = (z == 0) ? Wq : (z == 1) ? Wk : (z == 2) ? Wv : Wo;
        d = Wbf + (z << 20);
        t = bb * 256 + threadIdx.x;
    }
    float4 a = *((const float4*)s + t * 2);
    float4 c = *((const float4*)s + t * 2 + 1);
    u16x8 o;
    o[0] = f2bf(a.x); o[1] = f2bf(a.y); o[2] = f2bf(a.z); o[3] = f2bf(a.w);
    o[4] = f2bf(c.x); o[5] = f2bf(c.y); o[6] = f2bf(c.z); o[7] = f2bf(c.w);
    *((u16x8*)d + t) = o;
}

// ---------------------------------------------------------------- QKV GEMM (bf16 in)
// 2-wave blocks, 128x64 tile, grid (32, 48). 3-buffer counted-vmcnt pipeline.
__global__ __launch_bounds__(128) void gemm_qkv(
    const unsigned short* __restrict__ Xbf, const unsigned short* __restrict__ Wbf,
    const float* __restrict__ pos,
    unsigned short* __restrict__ qb, unsigned short* __restrict__ kb,
    unsigned short* __restrict__ vt)
{
    const int y = blockIdx.y;
    const int z = y >> 4;
    const unsigned short* __restrict__ W = Wbf + (z << 20);
    __shared__ unsigned short L[3][192 * 64];   // 24KB x 3 = 72KB
    const int t = threadIdx.x;                  // 0..127
    const int lane = t & 63;
    const int w = t >> 6;                       // 0..1
    const int m0 = blockIdx.x * 128;
    const int n0 = (y & 15) * 64;
    const int ll = lane & 15, lg = lane >> 4;
    const int r8 = lane >> 3, ch = (lane & 7) ^ r8;   // pre-swizzled source chunk

    f32x4 acc[4][4] = {};

    const unsigned short* gA[8];
    const unsigned short* gB[4];
    #pragma unroll
    for (int i = 0; i < 8; i++) gA[i] = Xbf + (m0 + w * 64 + i * 8 + r8) * 1024 + ch * 8;
    #pragma unroll
    for (int i = 0; i < 4; i++) gB[i] = W + (n0 + w * 32 + i * 8 + r8) * 1024 + ch * 8;

    const int sw0 = ((0 * 4 + lg) ^ (ll & 7)) * 16;
    const int sw1 = ((1 * 4 + lg) ^ (ll & 7)) * 16;

    auto stage = [&](unsigned short* Lb) {
        unsigned short* const dA = Lb + (w * 64) * 64;
        unsigned short* const dB = Lb + 128 * 64 + (w * 32) * 64;
        #pragma unroll
        for (int i = 0; i < 8; i++) { gl16(gA[i], dA + i * 8 * 64); gA[i] += 64; }
        #pragma unroll
        for (int i = 0; i < 4; i++) { gl16(gB[i], dB + i * 8 * 64); gB[i] += 64; }
    };
    auto compute = [&](const unsigned short* Lb) {
        const char* const pA0 = (const char*)Lb + (w * 64 + ll) * 128 + sw0;
        const char* const pA1 = (const char*)Lb + (w * 64 + ll) * 128 + sw1;
        const char* const pB0 = (const char*)Lb + 16384 + ll * 128 + sw0;
        const char* const pB1 = (const char*)Lb + 16384 + ll * 128 + sw1;
        u16x8 af[4], bfv[4];
        #pragma unroll
        for (int m = 0; m < 4; m++) af[m] = *(const u16x8*)(pA0 + m * 2048);
        #pragma unroll
        for (int n = 0; n < 4; n++) bfv[n] = *(const u16x8*)(pB0 + n * 2048);
        __builtin_amdgcn_s_setprio(1);
        #pragma unroll
        for (int m = 0; m < 4; m++)
            #pragma unroll
            for (int n = 0; n < 4; n++)
                acc[m][n] = mfma16(af[m], bfv[n], acc[m][n]);
        __builtin_amdgcn_s_setprio(0);
        #pragma unroll
        for (int m = 0; m < 4; m++) af[m] = *(const u16x8*)(pA1 + m * 2048);
        #pragma unroll
        for (int n = 0; n < 4; n++) bfv[n] = *(const u16x8*)(pB1 + n * 2048);
        __builtin_amdgcn_s_setprio(1);
        #pragma unroll
        for (int m = 0; m < 4; m++)
            #pragma unroll
            for (int n = 0; n < 4; n++)
                acc[m][n] = mfma16(af[m], bfv[n], acc[m][n]);
        __builtin_amdgcn_s_setprio(0);
    };

    stage(L[0]);
    stage(L[1]);
    PIPE_BAR_12();
    for (int tt = 0; tt < 4; tt++) {
        stage(L[2]); compute(L[0]); PIPE_BAR_12();
        stage(L[0]); compute(L[1]); PIPE_BAR_12();
        stage(L[1]); compute(L[2]); PIPE_BAR_12();
    }
    stage(L[2]); compute(L[0]); PIPE_BAR_12();
    stage(L[0]); compute(L[1]); PIPE_BAR_12();
    compute(L[2]); PIPE_BAR_0();
    compute(L[0]);

    if (z == 2) {
        #pragma unroll
        for (int m = 0; m < 4; m++) {
            const int row0 = m0 + w * 64 + m * 16 + lg * 4;
            const int b = row0 >> 11, s0 = row0 & 2047;
            #pragma unroll
            for (int n = 0; n < 4; n++) {
                const int c = n0 + n * 16 + ll;      // h*64 + d
                const int h = c >> 6, d = c & 63;
                unsigned long long pk =
                    (unsigned long long)cvtpk(acc[m][n][0], acc[m][n][1]) |
                    ((unsigned long long)cvtpk(acc[m][n][2], acc[m][n][3]) << 32);
                *(unsigned long long*)&vt[(((b * NHEADS + h) * 64) + d) * S_LEN + s0] = pk;
            }
        }
    } else {
        unsigned short* const dst = (z == 0) ? qb : kb;
        #pragma unroll
        for (int m = 0; m < 4; m++) {
            #pragma unroll
            for (int n = 0; n < 4; n++) {
                #pragma unroll
                for (int r = 0; r < 4; r++) {
                    const int row = m0 + w * 64 + m * 16 + lg * 4 + r;
                    const int c = n0 + n * 16 + ll;
                    const int b = row >> 11, s = row & 2047;
                    const int h = c >> 6, d = c & 63;
                    float v = acc[m][n][r] + pos[s * 64 + d];
                    if (z == 0) v *= 0.1803368801111244f;
                    dst[(((b * NHEADS + h) * S_LEN) + s) * 64 + d] = f2bf(v);
                }
            }
        }
    }
}

// ---------------------------------------------------------------- attention
// grid (16 qt, 32 bh), 8 waves x 512 thr, QBLK=128 (wave owns 16 q-rows).
// KVBLK=128: one barrier interval covers 128 KV rows (two 64-halves run
// back-to-back). K[2][128x64] + V^T[2][64x128] double-buffered (64KB) +
// per-wave P (16KB) = 80KB. Diagonal 128-tile peeled; waves 0-3 skip its
// fully-masked second half. Fixed-shift softmax exp2(sc).
__global__ __launch_bounds__(512, 4) void attn_kernel(
    const unsigned short* __restrict__ qb,
    const unsigned short* __restrict__ kb,
    const unsigned short* __restrict__ vt,
    unsigned short* __restrict__ attnb)
{
    __shared__ unsigned short Klds[2][128 * 64];   // 16KB each
    __shared__ unsigned short Vlds[2][64 * 128];   // 16KB each (row=d, 128 s-cols)
    __shared__ unsigned short Plds[8][16 * 64];    // per-wave 2KB; total 80KB

    const int bh = blockIdx.y;
    const int x = blockIdx.x;
    const int qt = (bh < 16) ? (15 - x) : x;      // pair long+short across halves

    const int lane = threadIdx.x & 63;
    const int w = threadIdx.x >> 6;               // 0..7
    const int lg = lane >> 4, ll = lane & 15;
    const int r8 = lane >> 3, ch = (lane & 7) ^ r8;
    const int r4 = lane >> 4, c16 = lane & 15;    // V-stage decomposition

    const unsigned short* Q = qb + bh * (S_LEN * 64);
    const unsigned short* K = kb + bh * (S_LEN * 64);
    const unsigned short* V = vt + bh * (64 * S_LEN);
    const int q0 = qt * 128 + w * 16;             // wave q-base

    u16x8 qf0 = *(const u16x8*)(Q + (q0 + ll) * 64 + lg * 8);
    u16x8 qf1 = *(const u16x8*)(Q + (q0 + ll) * 64 + 32 + lg * 8);

    f32x4 o_acc[4] = {};
    float l_part = 0.0f;

    // ---- precomputed LDS byte addresses ----
    const int sw0 = ((0 * 4 + lg) ^ (ll & 7)) * 16;
    const int sw1 = ((1 * 4 + lg) ^ (ll & 7)) * 16;
    // K read (row stride 128B): base + ll*128 + sw ; half1 = +8192 ; f-stride 2048
    const char* kb0p0 = (const char*)&Klds[0][0] + ll * 128 + sw0;
    const char* kb0p1 = (const char*)&Klds[0][0] + ll * 128 + sw1;
    const char* kb1p0 = (const char*)&Klds[1][0] + ll * 128 + sw0;
    const char* kb1p1 = (const char*)&Klds[1][0] + ll * 128 + sw1;
    // V read (row stride 256B): base + ll*256 + sw ; half1 = +128 ; f-stride 4096
    const char* vb0p0 = (const char*)&Vlds[0][0] + ll * 256 + sw0;
    const char* vb0p1 = (const char*)&Vlds[0][0] + ll * 256 + sw1;
    const char* vb1p0 = (const char*)&Vlds[1][0] + ll * 256 + sw0;
    const char* vb1p1 = (const char*)&Vlds[1][0] + ll * 256 + sw1;
    // P write: addr = ((ll*128+lg*8) ^ (E&16)) + ((f*32) ^ (E&96)),  E=(ll&7)<<4
    const int E = (ll & 7) << 4;
    char* pwb = (char*)&Plds[w][0] + (((ll * 128) + lg * 8) ^ (E & 16));
    const int pw_o0 = 0 ^ (E & 96), pw_o1 = 32 ^ (E & 96);
    const int pw_o2 = 64 ^ (E & 96), pw_o3 = 96 ^ (E & 96);
    const char* pr0 = (const char*)&Plds[w][0] + ll * 128 + sw0;
    const char* pr1 = (const char*)&Plds[w][0] + ll * 128 + sw1;
    // staging: K rows [w*16, +16) = 2 gl16; V rows [w*8, +8) = 2 gl16 (4 rows each)
    unsigned short* kd0 = &Klds[0][(w * 16) * 64];
    unsigned short* kd1 = &Klds[1][(w * 16) * 64];
    unsigned short* vd0 = &Vlds[0][(w * 8) * 128];
    unsigned short* vd1 = &Vlds[1][(w * 8) * 128];
    const unsigned short* gk  = K + (w * 16 + r8) * 64 + ch * 8;
    const unsigned short* gva = V + (w * 8 + r4) * S_LEN + ((c16 ^ r4) * 8);
    const unsigned short* gvb = V + (w * 8 + 4 + r4) * S_LEN + ((c16 ^ (4 + r4)) * 8);
    // diagonal thresholds: half0 thr = dthr, half1 thr = dthr - 64
    const int dthr = w * 16 + ll - lg * 4;

    auto stage2 = [&](unsigned short* kd, unsigned short* vd) {
        gl16(gk, kd);
        gl16(gk + 512, kd + 512);      // K rows +8
        gl16(gva, vd);
        gl16(gvb, vd + 512);           // V rows +4
        gk += 128 * 64;                // next 128-KV tile
        gva += 128;
        gvb += 128;
    };

    auto tile_body = [&](const char* kp0, const char* kp1,
                         const char* vp0, const char* vp1, bool masked, int thr) {
        f32x4 sc[4] = {};
        __builtin_amdgcn_s_setprio(1);
        #pragma unroll
        for (int f = 0; f < 4; f++) {
            const u16x8 kfa = *(const u16x8*)(kp0 + f * 2048);
            sc[f] = mfma16(kfa, qf0, sc[f]);
            const u16x8 kfb = *(const u16x8*)(kp1 + f * 2048);
            sc[f] = mfma16(kfb, qf1, sc[f]);
        }
        __builtin_amdgcn_s_setprio(0);
        if (masked) {
            #pragma unroll
            for (int f = 0; f < 4; f++)
                #pragma unroll
                for (int r = 0; r < 4; r++)
                    if (f * 16 + r > thr) sc[f][r] = -1.0e9f;
        }
        float ts = 0.0f;
        #pragma unroll
        for (int f = 0; f < 4; f++)
            #pragma unroll
            for (int r = 0; r < 4; r++) {
                const float p = __builtin_amdgcn_exp2f(sc[f][r]);
                sc[f][r] = p;
                ts += p;
            }
        l_part += ts;
        *(unsigned long long*)(pwb + pw_o0) =
            (unsigned long long)cvtpk(sc[0][0], sc[0][1]) | ((unsigned long long)cvtpk(sc[0][2], sc[0][3]) << 32);
        *(unsigned long long*)(pwb + pw_o1) =
            (unsigned long long)cvtpk(sc[1][0], sc[1][1]) | ((unsigned long long)cvtpk(sc[1][2], sc[1][3]) << 32);
        *(unsigned long long*)(pwb + pw_o2) =
            (unsigned long long)cvtpk(sc[2][0], sc[2][1]) | ((unsigned long long)cvtpk(sc[2][2], sc[2][3]) << 32);
        *(unsigned long long*)(pwb + pw_o3) =
            (unsigned long long)cvtpk(sc[3][0], sc[3][1]) | ((unsigned long long)cvtpk(sc[3][2], sc[3][3]) << 32);
        const u16x8 pf0 = *(const u16x8*)pr0;
        const u16x8 pf1 = *(const u16x8*)pr1;
        __builtin_amdgcn_s_setprio(1);
        #pragma unroll
        for (int f = 0; f < 4; f++) {
            o_acc[f] = mfma16(pf0, *(const u16x8*)(vp0 + f * 4096), o_acc[f]);
            o_acc[f] = mfma16(pf1, *(const u16x8*)(vp1 + f * 4096), o_acc[f]);
        }
        __builtin_amdgcn_s_setprio(0);
    };

    // body over one 128-KV buffer: two 64-halves
    auto body128_full = [&](const char* kp0, const char* kp1,
                            const char* vp0, const char* vp1) {
        tile_body(kp0, kp1, vp0, vp1, false, 0);
        tile_body(kp0 + 8192, kp1 + 8192, vp0 + 128, vp1 + 128, false, 0);
    };
    auto body128_diag = [&](const char* kp0, const char* kp1,
                            const char* vp0, const char* vp1) {
        tile_body(kp0, kp1, vp0, vp1, true, dthr);
        if (w >= 4)   // waves 0-3: second half fully masked
            tile_body(kp0 + 8192, kp1 + 8192, vp0 + 128, vp1 + 128, true, dthr - 64);
    };

    stage2(kd0, vd0);                      // tile 0 -> buf0
    __syncthreads();                       // buf0 ready

    int p = 0;
    while (p + 2 <= qt) {                  // two full 128-tiles
        stage2(kd1, vd1);                  // tile p+1 -> buf1
        body128_full(kb0p0, kb0p1, vb0p0, vb0p1);
        __syncthreads();                   // drains stage(p+1); buf1 ready
        stage2(kd0, vd0);                  // tile p+2 -> buf0
        body128_full(kb1p0, kb1p1, vb1p0, vb1p1);
        __syncthreads();                   // drains stage(p+2); buf0 ready
        p += 2;
    }
    if (p < qt) {                          // one full tile (p, buf0) + diag (buf1)
        stage2(kd1, vd1);                  // tile qt -> buf1
        body128_full(kb0p0, kb0p1, vb0p0, vb0p1);
        __syncthreads();
        body128_diag(kb1p0, kb1p1, vb1p0, vb1p1);
    } else {                               // diag in buf0
        body128_diag(kb0p0, kb0p1, vb0p0, vb0p1);
    }

    // one-time l reduction: lane (lg,ll) holds partial over its kv-subset of q=ll
    l_part += __shfl_xor(l_part, 16);
    l_part += __shfl_xor(l_part, 32);

    const int bb = bh >> 4, h = bh & 15;
    float lr0 = 1.0f / __shfl(l_part, lg * 4 + 0);
    float lr1 = 1.0f / __shfl(l_part, lg * 4 + 1);
    float lr2 = 1.0f / __shfl(l_part, lg * 4 + 2);
    float lr3 = 1.0f / __shfl(l_part, lg * 4 + 3);
    #pragma unroll
    for (int f = 0; f < 4; f++) {
        const int colbase = h * 64 + f * 16 + ll;
        attnb[(bb * S_LEN + q0 + lg * 4 + 0) * DMODEL + colbase] = f2bf(o_acc[f][0] * lr0);
        attnb[(bb * S_LEN + q0 + lg * 4 + 1) * DMODEL + colbase] = f2bf(o_acc[f][1] * lr1);
        attnb[(bb * S_LEN + q0 + lg * 4 + 2) * DMODEL + colbase] = f2bf(o_acc[f][2] * lr2);
        attnb[(bb * S_LEN + q0 + lg * 4 + 3) * DMODEL + colbase] = f2bf(o_acc[f][3] * lr3);
    }
}

// ---------------------------------------------------------------- out GEMM
// out = attn @ Wo^T + X. 3-buffer counted-vmcnt pipeline, 2-wave 128x64.
__global__ __launch_bounds__(128) void gemm_out(
    const unsigned short* __restrict__ Abf,
    const unsigned short* __restrict__ Wbf,
    const float* __restrict__ X,
    float* __restrict__ out)
{
    const unsigned short* __restrict__ W = Wbf + (3u << 20);
    __shared__ unsigned short L[3][192 * 64];   // 72KB
    const int t = threadIdx.x;
    const int lane = t & 63;
    const int w = t >> 6;
    const int m0 = blockIdx.x * 128;
    const int n0 = blockIdx.y * 64;
    const int ll = lane & 15, lg = lane >> 4;
    const int r8 = lane >> 3, ch = (lane & 7) ^ r8;

    f32x4 acc[4][4] = {};

    const unsigned short* gA[8];
    const unsigned short* gB[4];
    #pragma unroll
    for (int i = 0; i < 8; i++) gA[i] = Abf + (m0 + w * 64 + i * 8 + r8) * 1024 + ch * 8;
    #pragma unroll
    for (int i = 0; i < 4; i++) gB[i] = W + (n0 + w * 32 + i * 8 + r8) * 1024 + ch * 8;

    const int sw0 = ((0 * 4 + lg) ^ (ll & 7)) * 16;
    const int sw1 = ((1 * 4 + lg) ^ (ll & 7)) * 16;

    auto stage = [&](unsigned short* Lb) {
        unsigned short* const dA = Lb + (w * 64) * 64;
        unsigned short* const dB = Lb + 128 * 64 + (w * 32) * 64;
        #pragma unroll
        for (int i = 0; i < 8; i++) { gl16(gA[i], dA + i * 8 * 64); gA[i] += 64; }
        #pragma unroll
        for (int i = 0; i < 4; i++) { gl16(gB[i], dB + i * 8 * 64); gB[i] += 64; }
    };
    auto compute = [&](const unsigned short* Lb) {
        const char* const pA0 = (const char*)Lb + (w * 64 + ll) * 128 + sw0;
        const char* const pA1 = (const char*)Lb + (w * 64 + ll) * 128 + sw1;
        const char* const pB0 = (const char*)Lb + 16384 + ll * 128 + sw0;
        const char* const pB1 = (const char*)Lb + 16384 + ll * 128 + sw1;
        u16x8 af[4], bfv[4];
        #pragma unroll
        for (int m = 0; m < 4; m++) af[m] = *(const u16x8*)(pA0 + m * 2048);
        #pragma unroll
        for (int n = 0; n < 4; n++) bfv[n] = *(const u16x8*)(pB0 + n * 2048);
        __builtin_amdgcn_s_setprio(1);
        #pragma unroll
        for (int m = 0; m < 4; m++)
            #pragma unroll
            for (int n = 0; n < 4; n++)
                acc[m][n] = mfma16(af[m], bfv[n], acc[m][n]);
        __builtin_amdgcn_s_setprio(0);
        #pragma unroll
        for (int m = 0; m < 4; m++) af[m] = *(const u16x8*)(pA1 + m * 2048);
        #pragma unroll
        for (int n = 0; n < 4; n++) bfv[n] = *(const u16x8*)(pB1 + n * 2048);
        __builtin_amdgcn_s_setprio(1);
        #pragma unroll
        for (int m = 0; m < 4; m++)
            #pragma unroll
            for (int n = 0; n < 4; n++)
                acc[m][n] = mfma16(af[m], bfv[n], acc[m][n]);
        __builtin_amdgcn_s_setprio(0);
    };

    stage(L[0]);
    stage(L[1]);
    PIPE_BAR_12();
    for (int tt = 0; tt < 4; tt++) {
        stage(L[2]); compute(L[0]); PIPE_BAR_12();
        stage(L[0]); compute(L[1]); PIPE_BAR_12();
        stage(L[1]); compute(L[2]); PIPE_BAR_12();
    }
    stage(L[2]); compute(L[0]); PIPE_BAR_12();
    stage(L[0]); compute(L[1]); PIPE_BAR_12();
    compute(L[2]); PIPE_BAR_0();
    compute(L[0]);

    #pragma unroll
    for (int m = 0; m < 4; m++)
        #pragma unroll
        for (int n = 0; n < 4; n++)
            #pragma unroll
            for (int r = 0; r < 4; r++) {
                const int row = m0 + w * 64 + m * 16 + lg * 4 + r;
                const int col = n0 + n * 16 + ll;
                out[row * 1024 + col] = acc[m][n][r] + X[row * 1024 + col];
            }
}

// ---------------------------------------------------------------- launch
extern "C" void kernel_launch(void* const* d_in, const int* in_sizes, int n_in,
                              void* d_out, int out_size, void* d_ws, size_t ws_size,
                              hipStream_t stream) {
    const float* X  = (const float*)d_in[0];
    const float* Wq = (const float*)d_in[1];
    const float* Wk = (const float*)d_in[2];
    const float* Wv = (const float*)d_in[3];
    const float* Wo = (const float*)d_in[4];
    float* out = (float*)d_out;

    char* ws = (char*)d_ws;
    float*          pos  = (float*)(ws);                                   // 512 KB
    unsigned short* Xbf  = (unsigned short*)(ws + (512u << 10));           // 8 MB (reused as attb)
    unsigned short* Wbf  = (unsigned short*)(ws + (512u << 10) + (8u  << 20));  // 8 MB (4 stacked)
    unsigned short* qb   = (unsigned short*)(ws + (512u << 10) + (16u << 20));
    unsigned short* kb   = (unsigned short*)(ws + (512u << 10) + (24u << 20));
    unsigned short* vt   = (unsigned short*)(ws + (512u << 10) + (32u << 20));
    unsigned short* attb = Xbf;   // Xbf dead after gemm_qkv; reuse for attn output

    cvt5<<<dim3(4608), dim3(256), 0, stream>>>(X, Wq, Wk, Wv, Wo, Xbf, Wbf, pos);
    gemm_qkv<<<dim3(32, 48), dim3(128), 0, stream>>>(Xbf, Wbf, pos, qb, kb, vt);
    attn_kernel<<<dim3(16, 32), dim3(512), 0, stream>>>(qb, kb, vt, attb);
    gemm_out<<<dim3(32, 16), dim3(128), 0, stream>>>(attb, Wbf, X, out);
}